// Round 17
// baseline (130.160 us; speedup 1.0000x reference)
//
#include <hip/hip_runtime.h>

#define B_ 8
#define N_ 4096
#define F_ 512

typedef __attribute__((ext_vector_type(8))) short bf16x8;
typedef __attribute__((ext_vector_type(4))) float f32x4;

#define XPAD 524   // u16 row stride: 262 dw == 6 mod 32 -> distinct lane banks; 8B-aligned

// S (512 x 64) = [left | right | left_local | right_local], each [512][16] row-major.
__device__ __forceinline__ float Sval(const float* l, const float* r,
                                      const float* ll, const float* rl,
                                      int h, int e) {
    const int m = e >> 4, c = e & 15;
    const float* p = (m == 0) ? l : (m == 1) ? r : (m == 2) ? ll : rl;
    return p[h * 16 + c];
}

__device__ __forceinline__ float qval(const float* coeff, const float* coeff_l,
                                      int b, int j) {
    if (j < 16) return 1.f;
    if (j < 32) return coeff[b * 16 + (j - 16)];
    if (j < 48) return 1.f;
    return coeff_l[b * 16 + (j - 48)];
}

__device__ __forceinline__ float lane_bcast(float v, int lane) {
    return __int_as_float(__builtin_amdgcn_readlane(__float_as_int(v), lane));
}

__device__ __forceinline__ unsigned short bf16_rn(float x) {
    unsigned u = __float_as_uint(x);
    unsigned r = u + 0x7FFFu + ((u >> 16) & 1u);
    return (unsigned short)(r >> 16);
}

// split x ~= hi + lo, both bf16 (error ~2^-17 |x|)
__device__ __forceinline__ void bf16_split(float x, short& hi, short& lo) {
    const unsigned short h = bf16_rn(x);
    const float hf = __uint_as_float(((unsigned)h) << 16);
    const unsigned short s = bf16_rn(x - hf);
    hi = (short)h; lo = (short)s;
}

__device__ __forceinline__ float b2f(unsigned short u) {
    return __uint_as_float(((unsigned)u) << 16);
}

// ---- k_prep: GS row i + S-fragment f2=i for phase-2 B-operand. grid 64.
__global__ __launch_bounds__(256) void k_prep(const float* l, const float* r,
                                              const float* ll, const float* rl,
                                              float* GS, unsigned short* Sf) {
    __shared__ float red[4][64];
    const int i = blockIdx.x;
    const int t = threadIdx.x;
    const int j = t & 63, seg = t >> 6;

    {
        const int ht = i >> 1, eh = i & 1;
        for (int idx = t; idx < 512; idx += 256) {
            const int lx = idx >> 3, ii = idx & 7;
            const int h = ht * 16 + (lx & 15);
            const int e = eh * 32 + ((lx >> 4) & 3) * 8 + ii;
            short hh, ss;
            bf16_split(Sval(l, r, ll, rl, h, e), hh, ss);
            Sf[(i * 2 + 0) * 512 + idx] = (unsigned short)hh;
            Sf[(i * 2 + 1) * 512 + idx] = (unsigned short)ss;
        }
    }

    float acc = 0.f;
    const int h0 = seg * 128;
    for (int h = h0; h < h0 + 128; ++h)
        acc += Sval(l, r, ll, rl, h, i) * Sval(l, r, ll, rl, h, j);
    red[seg][j] = acc;
    __syncthreads();
    if (t < 64) GS[i * 64 + t] = red[0][t] + red[1][t] + red[2][t] + red[3][t];
}

// ---- GJ literal-index macros (rule #20: loop-var indices -> scratch; R15's
// fused GJ spilled exactly like R1/R2/R10 — FETCH ~900KB, VALUBusy <1%).
#define DO16(M) M(0) M(1) M(2) M(3) M(4) M(5) M(6) M(7) \
                M(8) M(9) M(10) M(11) M(12) M(13) M(14) M(15)

#define GJL(I) a[I] = Ms[(wv * 16 + (I)) * 64 + ln];
#define GJS(I) Ks[(wv * 16 + (I)) * 64 + ln] = a[I];

#define IP_UPD(I, BQ, J) \
    if ((I) != (J)) { \
        const float f_ = lane_bcast(a[(BQ) + (I)], g8 + (J)); \
        a[(BQ) + (I)] = __builtin_fmaf(-f_, akp##J, a[(BQ) + (I)]); \
    }

#define IP_STEP(BQ, J) { \
    const float dk = lane_bcast(a[(BQ) + (J)], g8 + (J)); \
    const float pinv = 1.0f / dk; \
    a[(BQ) + (J)] = (ln == g8 + (J)) ? pinv : a[(BQ) + (J)] * pinv; \
    akp##J = a[(BQ) + (J)] + ((ln == g8 + (J)) ? 1.0f : 0.0f); \
    akp_lds[(J) * 64 + ln] = akp##J; \
    IP_UPD(0, BQ, J) IP_UPD(1, BQ, J) IP_UPD(2, BQ, J) IP_UPD(3, BQ, J) \
    IP_UPD(4, BQ, J) IP_UPD(5, BQ, J) IP_UPD(6, BQ, J) IP_UPD(7, BQ, J) }

#define IP_ALL(BQ) \
    IP_STEP(BQ, 0) IP_STEP(BQ, 1) IP_STEP(BQ, 2) IP_STEP(BQ, 3) \
    IP_STEP(BQ, 4) IP_STEP(BQ, 5) IP_STEP(BQ, 6) IP_STEP(BQ, 7)

#define TRAIL(I) \
    if (((wv * 16 + (I)) >> 3) != G) { \
        const float f0 = lane_bcast(a[I], g8 + 0); \
        const float f1 = lane_bcast(a[I], g8 + 1); \
        const float f2 = lane_bcast(a[I], g8 + 2); \
        const float f3 = lane_bcast(a[I], g8 + 3); \
        const float f4 = lane_bcast(a[I], g8 + 4); \
        const float f5 = lane_bcast(a[I], g8 + 5); \
        const float f6 = lane_bcast(a[I], g8 + 6); \
        const float f7 = lane_bcast(a[I], g8 + 7); \
        a[I] = __builtin_fmaf(-f0, akp0, a[I]); \
        a[I] = __builtin_fmaf(-f1, akp1, a[I]); \
        a[I] = __builtin_fmaf(-f2, akp2, a[I]); \
        a[I] = __builtin_fmaf(-f3, akp3, a[I]); \
        a[I] = __builtin_fmaf(-f4, akp4, a[I]); \
        a[I] = __builtin_fmaf(-f5, akp5, a[I]); \
        a[I] = __builtin_fmaf(-f6, akp6, a[I]); \
        a[I] = __builtin_fmaf(-f7, akp7, a[I]); \
    }

// ---- k_solve: per-batch fused {build M/CP -> 4-wave blocked GJ -> Newton -> E ->
// SE -> SEf emission}, one phase-overlaid LDS. grid 8 (one block/b).
// Regions (floats): @0 GST->Tds | @4096 CPs->Es (live thru phase 8) |
// @8192 ABs->Ms->Tas->SEs(4160) | @12288 Ks ; Ss@12352(4224) |
// @16384 akp(512) | @16896 u1/u2.
__global__ __launch_bounds__(256) void k_solve(const float* coeff, const float* gate,
                                               const float* coeff_l, const float* gate_l,
                                               const float* comm, const float* GSg,
                                               const float* l, const float* r,
                                               const float* ll, const float* rl,
                                               unsigned short* SEf) {
    __shared__ float smem[17024];
    float* GST = smem;          // -> Tds
    float* CPs = smem + 4096;   // -> Es
    float* ABs = smem + 8192;   // -> Ms -> Tas -> SEs
    float* Ms  = smem + 8192;
    float* Ks  = smem + 12288;
    float* Tds = smem;
    float* Tas = smem + 8192;
    float* Es  = smem + 4096;
    float* SEs = smem + 8192;   // phase 8, stride 65 (4160f) [8192,12352)
    float* Ss  = smem + 12352;  // phase 8, stride 66 (4224f) [12352,16576)
    float* akp_lds = smem + 16384;
    float* u1s = smem + 16896;
    float* u2s = smem + 16928;

    const int b = blockIdx.x, t = threadIdx.x;
    const int tx = t & 15, ty = t >> 4;
    const float g = gate[b], gl = gate_l[b];
    const float cs = comm[b] / 12.0f;

    // (1) u1/u2 + GST
    if (t < 32) {
        u1s[t] = (t < 16) ? g * coeff[b * 16 + t] : -g;
        u2s[t] = (t < 16) ? gl * coeff_l[b * 16 + t] : -gl;
    }
    for (int idx = t; idx < 4096; idx += 256) {
        const int i = idx & 63, e = idx >> 6;
        GST[idx] = -0.5f * qval(coeff, coeff_l, b, i) * GSg[(i ^ 16) * 64 + e];
    }
    __syncthreads();

    // (2) ABs
    for (int idx = t; idx < 2048; idx += 256) {
        const int which = idx >> 10;
        const int i = (idx >> 5) & 31, j = idx & 31;
        float val;
        if (which == 0) {
            const int v2i = (i < 16) ? 48 + i : 16 + i;
            const float v2sc = (i < 16) ? 1.f : coeff_l[b * 16 + (i - 16)];
            val = v2sc * u1s[j] * GSg[v2i * 64 + j];
        } else {
            const int v1i = (i < 16) ? 16 + i : i - 16;
            const float v1sc = (i < 16) ? 1.f : coeff[b * 16 + (i - 16)];
            val = v1sc * u2s[j] * GSg[v1i * 64 + 32 + j];
        }
        ABs[idx] = val;
    }
    __syncthreads();

    // (3) CP
    for (int idx = t; idx < 4096; idx += 256) {
        const int e = idx >> 6, j = idx & 63;
        float val = 0.f;
        if (j < 32) {
            if (e == j) val += 0.5f * u1s[j];
            if (e >= 32) val += cs * u2s[e - 32] * ABs[(e - 32) * 32 + j];
        } else {
            const int jp = j - 32;
            if (e == 32 + jp) val += 0.5f * u2s[jp];
            if (e < 32) val -= cs * u1s[e] * ABs[1024 + e * 32 + jp];
        }
        CPs[idx] = val;
    }
    __syncthreads();   // ABs readers done

    // (4) M = I + GST^T*CP
    {
        const int i0 = ty * 4, m0 = tx * 4;
        float acc[4][4];
#pragma unroll
        for (int i = 0; i < 4; ++i)
#pragma unroll
            for (int j = 0; j < 4; ++j) acc[i][j] = 0.f;
        for (int e = 0; e < 64; ++e) {
            const float4 av = *reinterpret_cast<const float4*>(&GST[e * 64 + i0]);
            const float4 bv = *reinterpret_cast<const float4*>(&CPs[e * 64 + m0]);
            const float a[4] = {av.x, av.y, av.z, av.w};
            const float bb[4] = {bv.x, bv.y, bv.z, bv.w};
#pragma unroll
            for (int i = 0; i < 4; ++i)
#pragma unroll
                for (int j = 0; j < 4; ++j) acc[i][j] += a[i] * bb[j];
        }
#pragma unroll
        for (int i = 0; i < 4; ++i)
#pragma unroll
            for (int j = 0; j < 4; ++j)
                Ms[(i0 + i) * 64 + m0 + j] =
                    acc[i][j] + (((i0 + i) == (m0 + j)) ? 1.f : 0.f);
    }
    __syncthreads();

    // (5) 4-wave blocked Gauss-Jordan: Ms -> Ks. Wave wv owns rows 16wv..16wv+15
    // (a[16], ALL indices source-level literals). Owning wave runs in-panel
    // steps and publishes akp via LDS; trailing rows read multipliers via
    // wave-uniform readlane (g8+J is SGPR).
    {
        const int wv = t >> 6, ln = t & 63;
        float a[16];
        DO16(GJL)
        float akp0, akp1, akp2, akp3, akp4, akp5, akp6, akp7;
        for (int G = 0; G < 8; ++G) {
            const int g8 = G * 8;
            __syncthreads();   // prev akp readers done / buffer free
            if (wv == (G >> 1)) {
                if ((G & 1) == 0) { IP_ALL(0) } else { IP_ALL(8) }
            }
            __syncthreads();
            if (wv != (G >> 1)) {
                akp0 = akp_lds[0 * 64 + ln];
                akp1 = akp_lds[1 * 64 + ln];
                akp2 = akp_lds[2 * 64 + ln];
                akp3 = akp_lds[3 * 64 + ln];
                akp4 = akp_lds[4 * 64 + ln];
                akp5 = akp_lds[5 * 64 + ln];
                akp6 = akp_lds[6 * 64 + ln];
                akp7 = akp_lds[7 * 64 + ln];
            }
            DO16(TRAIL)
        }
        DO16(GJS)
    }
    __syncthreads();

    // (6) Td = CP*K -> @0 (GST dead) ; Ta = M*K -> @8192 (after barrier)
    {
        const int i0 = ty * 4, j0 = tx * 4;
        float accd[4][4], acca[4][4];
#pragma unroll
        for (int i = 0; i < 4; ++i)
#pragma unroll
            for (int j = 0; j < 4; ++j) { accd[i][j] = 0.f; acca[i][j] = 0.f; }
        for (int q = 0; q < 64; ++q) {
            const float4 bv = *reinterpret_cast<const float4*>(&Ks[q * 64 + j0]);
            const float bb[4] = {bv.x, bv.y, bv.z, bv.w};
            float ad[4], aa[4];
#pragma unroll
            for (int i = 0; i < 4; ++i) {
                ad[i] = CPs[(i0 + i) * 64 + q];
                aa[i] = Ms[(i0 + i) * 64 + q];
            }
#pragma unroll
            for (int i = 0; i < 4; ++i)
#pragma unroll
                for (int j = 0; j < 4; ++j) {
                    accd[i][j] += ad[i] * bb[j];
                    acca[i][j] += aa[i] * bb[j];
                }
        }
        __syncthreads();   // Ms readers done before Tas overwrite
#pragma unroll
        for (int i = 0; i < 4; ++i)
#pragma unroll
            for (int j = 0; j < 4; ++j) {
                Tds[(i0 + i) * 64 + j0 + j] = accd[i][j];
                Tas[(i0 + i) * 64 + j0 + j] = acca[i][j];
            }
    }
    __syncthreads();

    // (7) E[e][c^16] = q(c)*(2Td - Td*Ta)[e][c] -> @4096 (CPs dead)
    {
        const int e0 = ty * 4, c0 = tx * 4;
        float acc[4][4];
#pragma unroll
        for (int i = 0; i < 4; ++i)
#pragma unroll
            for (int j = 0; j < 4; ++j) acc[i][j] = 0.f;
        for (int q = 0; q < 64; ++q) {
            const float4 bv = *reinterpret_cast<const float4*>(&Tas[q * 64 + c0]);
            const float bb[4] = {bv.x, bv.y, bv.z, bv.w};
            float a[4];
#pragma unroll
            for (int i = 0; i < 4; ++i) a[i] = Tds[(e0 + i) * 64 + q];
#pragma unroll
            for (int i = 0; i < 4; ++i)
#pragma unroll
                for (int j = 0; j < 4; ++j) acc[i][j] += a[i] * bb[j];
        }
        float qv[4];
#pragma unroll
        for (int j = 0; j < 4; ++j) qv[j] = qval(coeff, coeff_l, b, c0 + j);
#pragma unroll
        for (int i = 0; i < 4; ++i) {
            float4 o;
            o.x = qv[0] * (2.f * Tds[(e0 + i) * 64 + c0 + 0] - acc[i][0]);
            o.y = qv[1] * (2.f * Tds[(e0 + i) * 64 + c0 + 1] - acc[i][1]);
            o.z = qv[2] * (2.f * Tds[(e0 + i) * 64 + c0 + 2] - acc[i][2]);
            o.w = qv[3] * (2.f * Tds[(e0 + i) * 64 + c0 + 3] - acc[i][3]);
            *reinterpret_cast<float4*>(&Es[(e0 + i) * 64 + (c0 ^ 16)]) = o;
        }
    }
    __syncthreads();

    // (8) SE chunks (hc=0..7): Ss -> SEs -> fragment emission. Es stays live.
    for (int hc = 0; hc < 8; ++hc) {
        for (int idx = t; idx < 4096; idx += 256) {
            const int hl_ = idx >> 6, e = idx & 63;
            Ss[hl_ * 66 + e] = Sval(l, r, ll, rl, hc * 64 + hl_, e);
        }
        __syncthreads();
        {
            const int h = t >> 2;
            const int mg = (t & 3) * 16;
            float acc[16];
#pragma unroll
            for (int q = 0; q < 16; ++q) acc[q] = 0.f;
#pragma unroll 4
            for (int e = 0; e < 64; ++e) {
                const float s = Ss[h * 66 + e];
                const float* Er = Es + e * 64 + mg;
#pragma unroll
                for (int q = 0; q < 16; ++q) acc[q] += s * Er[q];
            }
#pragma unroll
            for (int q = 0; q < 16; ++q) SEs[h * 65 + mg + q] = acc[q];
        }
        __syncthreads();
        unsigned short* outp = SEf + (size_t)b * 65536 + hc * 8192;
#pragma unroll
        for (int it = 0; it < 4; ++it) {
            const int widx0 = it * 2048 + t * 8;
            const int fl = widx0 >> 10;
            const int hl = (widx0 >> 9) & 1;
            const int lx = (widx0 >> 3) & 63;
            const int m = (fl & 3) * 16 + (lx & 15);
            const int hb = (fl >> 2) * 32 + ((lx >> 4) & 3) * 8;
            unsigned short wv[8];
#pragma unroll
            for (int i = 0; i < 8; ++i) {
                short hh, ss;
                bf16_split(SEs[(hb + i) * 65 + m], hh, ss);
                wv[i] = hl ? (unsigned short)ss : (unsigned short)hh;
            }
            uint4 pk;
            pk.x = (unsigned)wv[0] | ((unsigned)wv[1] << 16);
            pk.y = (unsigned)wv[2] | ((unsigned)wv[3] << 16);
            pk.z = (unsigned)wv[4] | ((unsigned)wv[5] << 16);
            pk.w = (unsigned)wv[6] | ((unsigned)wv[7] << 16);
            *reinterpret_cast<uint4*>(outp + widx0) = pk;
        }
        __syncthreads();  // SEs/Ss readers done before next chunk's writes
    }
}

// out = x + ((x * SE_b) * S^T) via split-bf16 MFMA, LDS-staged x (hi/lo),
// XPAD=524. Byte-identical to R13. grid (128, 8), 4 waves.
__global__ __launch_bounds__(256, 2) void k_mix(const float* x,
                                                const unsigned short* SEf,
                                                const unsigned short* Sf,
                                                float* out) {
    __shared__ unsigned short xh[32 * XPAD];
    __shared__ unsigned short xl[32 * XPAD];
    __shared__ float Zs[32 * 68];
    const int b = blockIdx.y;
    const int r0 = blockIdx.x * 32;
    const int t = threadIdx.x;
    const int w = t >> 6;
    const int l = t & 63;
    const int lm = l & 15;
    const int lk = (l >> 4) * 8;
    const int rw = w & 1, cw = w >> 1;
    const float* xb = x + (size_t)b * N_ * F_;
    float* outb = out + (size_t)b * N_ * F_;
    const unsigned short* sef = SEf + (size_t)b * 65536;

#pragma unroll 4
    for (int it = 0; it < 16; ++it) {
        const int idx = it * 256 + t;
        const int row = idx >> 7, c4 = (idx & 127) * 4;
        const float4 v = *reinterpret_cast<const float4*>(
            xb + (size_t)(r0 + row) * F_ + c4);
        ushort4 hs, ls;
        short hh, ss;
        bf16_split(v.x, hh, ss); hs.x = (unsigned short)hh; ls.x = (unsigned short)ss;
        bf16_split(v.y, hh, ss); hs.y = (unsigned short)hh; ls.y = (unsigned short)ss;
        bf16_split(v.z, hh, ss); hs.z = (unsigned short)hh; ls.z = (unsigned short)ss;
        bf16_split(v.w, hh, ss); hs.w = (unsigned short)hh; ls.w = (unsigned short)ss;
        *reinterpret_cast<ushort4*>(&xh[row * XPAD + c4]) = hs;
        *reinterpret_cast<ushort4*>(&xl[row * XPAD + c4]) = ls;
    }
    __syncthreads();

    f32x4 ahh0 = {0.f, 0.f, 0.f, 0.f}, alh0 = ahh0, ahl0 = ahh0;
    f32x4 ahh1 = ahh0, alh1 = ahh0, ahl1 = ahh0;
    const unsigned short* xhr = xh + (16 * rw + lm) * XPAD;
    const unsigned short* xlr = xl + (16 * rw + lm) * XPAD;
#pragma unroll 4
    for (int kk = 0; kk < 16; ++kk) {
        const int k0 = kk * 32 + lk;
        const bf16x8 ah = *reinterpret_cast<const bf16x8*>(xhr + k0);
        const bf16x8 al = *reinterpret_cast<const bf16x8*>(xlr + k0);
        const int o0 = (kk * 4 + 2 * cw) * 1024 + l * 8;
        const bf16x8 bh0 = *reinterpret_cast<const bf16x8*>(sef + o0);
        const bf16x8 bl0 = *reinterpret_cast<const bf16x8*>(sef + o0 + 512);
        const bf16x8 bh1 = *reinterpret_cast<const bf16x8*>(sef + o0 + 1024);
        const bf16x8 bl1 = *reinterpret_cast<const bf16x8*>(sef + o0 + 1536);
        ahh0 = __builtin_amdgcn_mfma_f32_16x16x32_bf16(ah, bh0, ahh0, 0, 0, 0);
        alh0 = __builtin_amdgcn_mfma_f32_16x16x32_bf16(al, bh0, alh0, 0, 0, 0);
        ahl0 = __builtin_amdgcn_mfma_f32_16x16x32_bf16(ah, bl0, ahl0, 0, 0, 0);
        ahh1 = __builtin_amdgcn_mfma_f32_16x16x32_bf16(ah, bh1, ahh1, 0, 0, 0);
        alh1 = __builtin_amdgcn_mfma_f32_16x16x32_bf16(al, bh1, alh1, 0, 0, 0);
        ahl1 = __builtin_amdgcn_mfma_f32_16x16x32_bf16(ah, bl1, ahl1, 0, 0, 0);
    }
#pragma unroll
    for (int r = 0; r < 4; ++r) {
        const int zr = (16 * rw + (l >> 4) * 4 + r) * 68 + 32 * cw;
        Zs[zr + lm] = ahh0[r] + alh0[r] + ahl0[r];
        Zs[zr + 16 + lm] = ahh1[r] + alh1[r] + ahl1[r];
    }
    __syncthreads();

    bf16x8 zh0, zl0, zh1, zl1;
    {
        const float* zrow = &Zs[(16 * rw + lm) * 68];
#pragma unroll
        for (int i = 0; i < 8; ++i) {
            short hh, ss;
            bf16_split(zrow[lk + i], hh, ss);
            zh0[i] = hh; zl0[i] = ss;
            bf16_split(zrow[32 + lk + i], hh, ss);
            zh1[i] = hh; zl1[i] = ss;
        }
    }
    const int lrow0 = 16 * rw + (l >> 4) * 4;
    const int orow0 = r0 + lrow0;
#pragma unroll 2
    for (int j2 = 0; j2 < 16; ++j2) {
        const int ht = cw * 16 + j2;
        const int h0 = ht * 16 + lm;
        f32x4 ca = {0.f, 0.f, 0.f, 0.f};
        f32x4 cb;
#pragma unroll
        for (int r = 0; r < 4; ++r) {
            const int la = (lrow0 + r) * XPAD + h0;
            cb[r] = b2f(xh[la]) + b2f(xl[la]);
        }
        const int fb = ht * 2048 + l * 8;
        const bf16x8 bh0 = *reinterpret_cast<const bf16x8*>(Sf + fb);
        const bf16x8 bl0 = *reinterpret_cast<const bf16x8*>(Sf + fb + 512);
        const bf16x8 bh1 = *reinterpret_cast<const bf16x8*>(Sf + fb + 1024);
        const bf16x8 bl1 = *reinterpret_cast<const bf16x8*>(Sf + fb + 1536);
        ca = __builtin_amdgcn_mfma_f32_16x16x32_bf16(zh0, bh0, ca, 0, 0, 0);
        ca = __builtin_amdgcn_mfma_f32_16x16x32_bf16(zl0, bh0, ca, 0, 0, 0);
        ca = __builtin_amdgcn_mfma_f32_16x16x32_bf16(zh0, bl0, ca, 0, 0, 0);
        cb = __builtin_amdgcn_mfma_f32_16x16x32_bf16(zh1, bh1, cb, 0, 0, 0);
        cb = __builtin_amdgcn_mfma_f32_16x16x32_bf16(zl1, bh1, cb, 0, 0, 0);
        cb = __builtin_amdgcn_mfma_f32_16x16x32_bf16(zh1, bl1, cb, 0, 0, 0);
#pragma unroll
        for (int r = 0; r < 4; ++r)
            outb[(size_t)(orow0 + r) * F_ + h0] = ca[r] + cb[r];
    }
}

extern "C" void kernel_launch(void* const* d_in, const int* in_sizes, int n_in,
                              void* d_out, int out_size, void* d_ws, size_t ws_size,
                              hipStream_t stream) {
    (void)in_sizes; (void)n_in; (void)out_size; (void)ws_size;
    const float* x       = (const float*)d_in[0];
    const float* coeff   = (const float*)d_in[1];
    const float* gate    = (const float*)d_in[2];
    const float* coeff_l = (const float*)d_in[3];
    const float* gate_l  = (const float*)d_in[4];
    const float* comm    = (const float*)d_in[5];
    const float* l       = (const float*)d_in[6];
    const float* r       = (const float*)d_in[7];
    const float* ll      = (const float*)d_in[8];
    const float* rl      = (const float*)d_in[9];

    char* wsb = (char*)d_ws;
    float* GS   = (float*)(wsb);                              // 4096 f       @0
    unsigned short* SEf = (unsigned short*)(wsb + 147456);    // 8*65536 u16  @144K (1MB)
    unsigned short* Sf  = (unsigned short*)(wsb + 1196032);   // 65536 u16    @1168K (128K)
    float* out = (float*)d_out;

    k_prep<<<dim3(64), dim3(256), 0, stream>>>(l, r, ll, rl, GS, Sf);
    k_solve<<<dim3(8), dim3(256), 0, stream>>>(coeff, gate, coeff_l, gate_l, comm, GS,
                                               l, r, ll, rl, SEf);
    k_mix<<<dim3(128, 8), dim3(256), 0, stream>>>(x, SEf, Sf, out);
}

// Round 18
// 112.064 us; speedup vs baseline: 1.1615x; 1.1615x over previous
//
#include <hip/hip_runtime.h>

#define B_ 8
#define N_ 4096
#define F_ 512

typedef __attribute__((ext_vector_type(8))) short bf16x8;
typedef __attribute__((ext_vector_type(4))) float f32x4;

#define XPAD 524   // u16 row stride: 262 dw == 6 mod 32 -> distinct lane banks; 8B-aligned

// S (512 x 64) = [left | right | left_local | right_local], each [512][16] row-major.
__device__ __forceinline__ float Sval(const float* l, const float* r,
                                      const float* ll, const float* rl,
                                      int h, int e) {
    const int m = e >> 4, c = e & 15;
    const float* p = (m == 0) ? l : (m == 1) ? r : (m == 2) ? ll : rl;
    return p[h * 16 + c];
}

__device__ __forceinline__ float qval(const float* coeff, const float* coeff_l,
                                      int b, int j) {
    if (j < 16) return 1.f;
    if (j < 32) return coeff[b * 16 + (j - 16)];
    if (j < 48) return 1.f;
    return coeff_l[b * 16 + (j - 48)];
}

__device__ __forceinline__ float lane_bcast(float v, int lane) {
    return __int_as_float(__builtin_amdgcn_readlane(__float_as_int(v), lane));
}

__device__ __forceinline__ unsigned short bf16_rn(float x) {
    unsigned u = __float_as_uint(x);
    unsigned r = u + 0x7FFFu + ((u >> 16) & 1u);
    return (unsigned short)(r >> 16);
}

// split x ~= hi + lo, both bf16 (error ~2^-17 |x|)
__device__ __forceinline__ void bf16_split(float x, short& hi, short& lo) {
    const unsigned short h = bf16_rn(x);
    const float hf = __uint_as_float(((unsigned)h) << 16);
    const unsigned short s = bf16_rn(x - hf);
    hi = (short)h; lo = (short)s;
}

__device__ __forceinline__ float b2f(unsigned short u) {
    return __uint_as_float(((unsigned)u) << 16);
}

// ---- k_prep: GS row i + S-fragment f2=i for phase-2 B-operand. grid 64.
__global__ __launch_bounds__(256) void k_prep(const float* l, const float* r,
                                              const float* ll, const float* rl,
                                              float* GS, unsigned short* Sf) {
    __shared__ float red[4][64];
    const int i = blockIdx.x;
    const int t = threadIdx.x;
    const int j = t & 63, seg = t >> 6;

    {
        const int ht = i >> 1, eh = i & 1;
        for (int idx = t; idx < 512; idx += 256) {
            const int lx = idx >> 3, ii = idx & 7;
            const int h = ht * 16 + (lx & 15);
            const int e = eh * 32 + ((lx >> 4) & 3) * 8 + ii;
            short hh, ss;
            bf16_split(Sval(l, r, ll, rl, h, e), hh, ss);
            Sf[(i * 2 + 0) * 512 + idx] = (unsigned short)hh;
            Sf[(i * 2 + 1) * 512 + idx] = (unsigned short)ss;
        }
    }

    float acc = 0.f;
    const int h0 = seg * 128;
    for (int h = h0; h < h0 + 128; ++h)
        acc += Sval(l, r, ll, rl, h, i) * Sval(l, r, ll, rl, h, j);
    red[seg][j] = acc;
    __syncthreads();
    if (t < 64) GS[i * 64 + t] = red[0][t] + red[1][t] + red[2][t] + red[3][t];
}

// ---- k_pre: build CP and M = I - 0.5 CQ^T GS CP -> Mws, CPws. 8 blocks.
__global__ __launch_bounds__(256) void k_pre(const float* coeff, const float* gate,
                                             const float* coeff_l, const float* gate_l,
                                             const float* comm, const float* GS,
                                             float* Mws, float* CPws) {
    __shared__ float GST[4096];
    __shared__ float CPs[4096];
    __shared__ float ABs[2048];
    __shared__ float u1s[32], u2s[32];

    const int b = blockIdx.x, t = threadIdx.x;
    const int tx = t & 15, ty = t >> 4;
    const float g = gate[b], gl = gate_l[b];
    const float cs = comm[b] / 12.0f;

    if (t < 32) {
        u1s[t] = (t < 16) ? g * coeff[b * 16 + t] : -g;
        u2s[t] = (t < 16) ? gl * coeff_l[b * 16 + t] : -gl;
    }
    for (int idx = t; idx < 4096; idx += 256) {
        const int i = idx & 63, e = idx >> 6;
        GST[idx] = -0.5f * qval(coeff, coeff_l, b, i) * GS[(i ^ 16) * 64 + e];
    }
    __syncthreads();

    for (int idx = t; idx < 2048; idx += 256) {
        const int which = idx >> 10;
        const int i = (idx >> 5) & 31, j = idx & 31;
        float val;
        if (which == 0) {
            const int v2i = (i < 16) ? 48 + i : 16 + i;
            const float v2sc = (i < 16) ? 1.f : coeff_l[b * 16 + (i - 16)];
            val = v2sc * u1s[j] * GS[v2i * 64 + j];
        } else {
            const int v1i = (i < 16) ? 16 + i : i - 16;
            const float v1sc = (i < 16) ? 1.f : coeff[b * 16 + (i - 16)];
            val = v1sc * u2s[j] * GS[v1i * 64 + 32 + j];
        }
        ABs[idx] = val;
    }
    __syncthreads();

    for (int idx = t; idx < 4096; idx += 256) {
        const int e = idx >> 6, j = idx & 63;
        float val = 0.f;
        if (j < 32) {
            if (e == j) val += 0.5f * u1s[j];
            if (e >= 32) val += cs * u2s[e - 32] * ABs[(e - 32) * 32 + j];
        } else {
            const int jp = j - 32;
            if (e == 32 + jp) val += 0.5f * u2s[jp];
            if (e < 32) val -= cs * u1s[e] * ABs[1024 + e * 32 + jp];
        }
        CPs[idx] = val;
        CPws[b * 4096 + idx] = val;
    }
    __syncthreads();

    {
        const int i0 = ty * 4, m0 = tx * 4;
        float acc[4][4];
#pragma unroll
        for (int i = 0; i < 4; ++i)
#pragma unroll
            for (int j = 0; j < 4; ++j) acc[i][j] = 0.f;
        for (int e = 0; e < 64; ++e) {
            const float4 av = *reinterpret_cast<const float4*>(&GST[e * 64 + i0]);
            const float4 bv = *reinterpret_cast<const float4*>(&CPs[e * 64 + m0]);
            const float a[4] = {av.x, av.y, av.z, av.w};
            const float bb[4] = {bv.x, bv.y, bv.z, bv.w};
#pragma unroll
            for (int i = 0; i < 4; ++i)
#pragma unroll
                for (int j = 0; j < 4; ++j) acc[i][j] += a[i] * bb[j];
        }
#pragma unroll
        for (int i = 0; i < 4; ++i) {
            float4 o;
            o.x = acc[i][0] + (((i0 + i) == (m0 + 0)) ? 1.f : 0.f);
            o.y = acc[i][1] + (((i0 + i) == (m0 + 1)) ? 1.f : 0.f);
            o.z = acc[i][2] + (((i0 + i) == (m0 + 2)) ? 1.f : 0.f);
            o.w = acc[i][3] + (((i0 + i) == (m0 + 3)) ? 1.f : 0.f);
            *reinterpret_cast<float4*>(&Mws[b * 4096 + (i0 + i) * 64 + m0]) = o;
        }
    }
}

// ---- k_inv: BLOCKED single-wave register Gauss-Jordan, 8 macro-steps, 0 barriers.
#define DO64(M, K) \
    M(0, K) M(1, K) M(2, K) M(3, K) M(4, K) M(5, K) M(6, K) M(7, K) \
    M(8, K) M(9, K) M(10, K) M(11, K) M(12, K) M(13, K) M(14, K) M(15, K) \
    M(16, K) M(17, K) M(18, K) M(19, K) M(20, K) M(21, K) M(22, K) M(23, K) \
    M(24, K) M(25, K) M(26, K) M(27, K) M(28, K) M(29, K) M(30, K) M(31, K) \
    M(32, K) M(33, K) M(34, K) M(35, K) M(36, K) M(37, K) M(38, K) M(39, K) \
    M(40, K) M(41, K) M(42, K) M(43, K) M(44, K) M(45, K) M(46, K) M(47, K) \
    M(48, K) M(49, K) M(50, K) M(51, K) M(52, K) M(53, K) M(54, K) M(55, K) \
    M(56, K) M(57, K) M(58, K) M(59, K) M(60, K) M(61, K) M(62, K) M(63, K)

#define GJ_LOAD(RR, K) a[RR] = Mws[base + (RR)*64 + t];
#define GJ_STORE(RR, K) Kws[base + (RR)*64 + t] = a[RR];

#define INV_SNAP(RR, G) if (ing) Msnap[(RR) * 8 + gl] = a[RR];

#define IGU(I, G, J) \
    if ((I) != (J)) { \
        const float f_ = lane_bcast(a[(G)*8 + (I)], (G)*8 + (J)); \
        a[(G)*8 + (I)] = __builtin_fmaf(-f_, akp[J], a[(G)*8 + (I)]); \
    }

#define IGS(G, J) { \
    const float dk = lane_bcast(a[(G)*8 + (J)], (G)*8 + (J)); \
    const float pinv = 1.0f / dk; \
    a[(G)*8 + (J)] = (t == ((G)*8 + (J))) ? pinv : a[(G)*8 + (J)] * pinv; \
    akp[J] = a[(G)*8 + (J)] + ((t == ((G)*8 + (J))) ? 1.0f : 0.0f); \
    IGU(0, G, J) IGU(1, G, J) IGU(2, G, J) IGU(3, G, J) \
    IGU(4, G, J) IGU(5, G, J) IGU(6, G, J) IGU(7, G, J) }

#define TRL(RR, G) \
    if (((RR) >> 3) != (G)) { \
        const float4 m0 = *reinterpret_cast<const float4*>(&Msnap[(RR) * 8]); \
        const float4 m1 = *reinterpret_cast<const float4*>(&Msnap[(RR) * 8 + 4]); \
        a[RR] = __builtin_fmaf(-m0.x, akp[0], a[RR]); \
        a[RR] = __builtin_fmaf(-m0.y, akp[1], a[RR]); \
        a[RR] = __builtin_fmaf(-m0.z, akp[2], a[RR]); \
        a[RR] = __builtin_fmaf(-m0.w, akp[3], a[RR]); \
        a[RR] = __builtin_fmaf(-m1.x, akp[4], a[RR]); \
        a[RR] = __builtin_fmaf(-m1.y, akp[5], a[RR]); \
        a[RR] = __builtin_fmaf(-m1.z, akp[6], a[RR]); \
        a[RR] = __builtin_fmaf(-m1.w, akp[7], a[RR]); \
    }

#define MACRO_STEP(G) { \
    float akp[8]; \
    const bool ing = ((t >> 3) == (G)); \
    DO64(INV_SNAP, G) \
    IGS(G, 0) IGS(G, 1) IGS(G, 2) IGS(G, 3) \
    IGS(G, 4) IGS(G, 5) IGS(G, 6) IGS(G, 7) \
    DO64(TRL, G) }

__global__ __launch_bounds__(64, 1) void k_inv(const float* Mws, float* Kws) {
    __shared__ float Msnap[512];
    const int b = blockIdx.x, t = threadIdx.x;  // lane t owns column t
    const int base = b * 4096;
    const int gl = t & 7;
    float a[64];
    DO64(GJ_LOAD, 0)
    MACRO_STEP(0) MACRO_STEP(1) MACRO_STEP(2) MACRO_STEP(3)
    MACRO_STEP(4) MACRO_STEP(5) MACRO_STEP(6) MACRO_STEP(7)
    DO64(GJ_STORE, 0)
}

// ---- k_sepost: fused Newton+E (per-b, redundantly per hc) and SE-chunk emission.
// grid (hc=8, b=8). LDS flat 80KB, phase-overlaid.
__global__ __launch_bounds__(256) void k_sepost(const float* coeff, const float* coeff_l,
                                                const float* l, const float* r,
                                                const float* ll, const float* rl,
                                                const float* Mws, const float* CPws,
                                                const float* Kws, unsigned short* SEf) {
    __shared__ float smem[20480];
    float* Ms  = smem;
    float* CPs = smem + 4096;
    float* Ks  = smem + 8192;
    float* Tds = smem + 12288;
    float* Tas = smem + 16384;
    float* Es  = smem;          // phase B
    float* Ss  = smem + 4096;   // phase B, stride 66 (4224 floats)
    float* SEs = smem + 8320;   // phase C, stride 65 (4160 floats)

    const int b = blockIdx.y, hc = blockIdx.x, t = threadIdx.x;
    const int tx = t & 15, ty = t >> 4;

    for (int idx = t; idx < 4096; idx += 256) {
        Ms[idx] = Mws[b * 4096 + idx];
        CPs[idx] = CPws[b * 4096 + idx];
        Ks[idx] = Kws[b * 4096 + idx];
    }
    __syncthreads();

    // Td = CP*K ; Ta = M*K
    {
        const int i0 = ty * 4, j0 = tx * 4;
        float accd[4][4], acca[4][4];
#pragma unroll
        for (int i = 0; i < 4; ++i)
#pragma unroll
            for (int j = 0; j < 4; ++j) { accd[i][j] = 0.f; acca[i][j] = 0.f; }
        for (int q = 0; q < 64; ++q) {
            const float4 bv = *reinterpret_cast<const float4*>(&Ks[q * 64 + j0]);
            const float bb[4] = {bv.x, bv.y, bv.z, bv.w};
            float ad[4], aa[4];
#pragma unroll
            for (int i = 0; i < 4; ++i) {
                ad[i] = CPs[(i0 + i) * 64 + q];
                aa[i] = Ms[(i0 + i) * 64 + q];
            }
#pragma unroll
            for (int i = 0; i < 4; ++i)
#pragma unroll
                for (int j = 0; j < 4; ++j) {
                    accd[i][j] += ad[i] * bb[j];
                    acca[i][j] += aa[i] * bb[j];
                }
        }
        __syncthreads();
#pragma unroll
        for (int i = 0; i < 4; ++i)
#pragma unroll
            for (int j = 0; j < 4; ++j) {
                Tds[(i0 + i) * 64 + j0 + j] = accd[i][j];
                Tas[(i0 + i) * 64 + j0 + j] = acca[i][j];
            }
    }
    __syncthreads();

    // E[e][c^16] = q(c)*(2Td - Td*Ta)[e][c] -> R0 ; Ss chunk -> R1+
    {
        const int e0 = ty * 4, c0 = tx * 4;
        float acc[4][4];
#pragma unroll
        for (int i = 0; i < 4; ++i)
#pragma unroll
            for (int j = 0; j < 4; ++j) acc[i][j] = 0.f;
        for (int q = 0; q < 64; ++q) {
            const float4 bv = *reinterpret_cast<const float4*>(&Tas[q * 64 + c0]);
            const float bb[4] = {bv.x, bv.y, bv.z, bv.w};
            float a[4];
#pragma unroll
            for (int i = 0; i < 4; ++i) a[i] = Tds[(e0 + i) * 64 + q];
#pragma unroll
            for (int i = 0; i < 4; ++i)
#pragma unroll
                for (int j = 0; j < 4; ++j) acc[i][j] += a[i] * bb[j];
        }
        float qv[4];
#pragma unroll
        for (int j = 0; j < 4; ++j) qv[j] = qval(coeff, coeff_l, b, c0 + j);
#pragma unroll
        for (int i = 0; i < 4; ++i) {
            float4 o;
            o.x = qv[0] * (2.f * Tds[(e0 + i) * 64 + c0 + 0] - acc[i][0]);
            o.y = qv[1] * (2.f * Tds[(e0 + i) * 64 + c0 + 1] - acc[i][1]);
            o.z = qv[2] * (2.f * Tds[(e0 + i) * 64 + c0 + 2] - acc[i][2]);
            o.w = qv[3] * (2.f * Tds[(e0 + i) * 64 + c0 + 3] - acc[i][3]);
            *reinterpret_cast<float4*>(&Es[(e0 + i) * 64 + (c0 ^ 16)]) = o;
        }
        for (int idx = t; idx < 4096; idx += 256) {
            const int hl_ = idx >> 6, e = idx & 63;
            Ss[hl_ * 66 + e] = Sval(l, r, ll, rl, hc * 64 + hl_, e);
        }
    }
    __syncthreads();

    // SE rows: SEs[h][m] = sum_e Ss[h][e]*Es[e][m]
    {
        const int h = t >> 2;
        const int mg = (t & 3) * 16;
        float acc[16];
#pragma unroll
        for (int q = 0; q < 16; ++q) acc[q] = 0.f;
#pragma unroll 4
        for (int e = 0; e < 64; ++e) {
            const float s = Ss[h * 66 + e];
            const float* Er = Es + e * 64 + mg;
#pragma unroll
            for (int q = 0; q < 16; ++q) acc[q] += s * Er[q];
        }
        __syncthreads();
#pragma unroll
        for (int q = 0; q < 16; ++q) SEs[h * 65 + mg + q] = acc[q];
    }
    __syncthreads();

    unsigned short* outp = SEf + (size_t)b * 65536 + hc * 8192;
#pragma unroll
    for (int it = 0; it < 4; ++it) {
        const int widx0 = it * 2048 + t * 8;
        const int fl = widx0 >> 10;
        const int hl = (widx0 >> 9) & 1;
        const int lx = (widx0 >> 3) & 63;
        const int m = (fl & 3) * 16 + (lx & 15);
        const int hb = (fl >> 2) * 32 + ((lx >> 4) & 3) * 8;
        unsigned short wv[8];
#pragma unroll
        for (int i = 0; i < 8; ++i) {
            short hh, ss;
            bf16_split(SEs[(hb + i) * 65 + m], hh, ss);
            wv[i] = hl ? (unsigned short)ss : (unsigned short)hh;
        }
        uint4 pk;
        pk.x = (unsigned)wv[0] | ((unsigned)wv[1] << 16);
        pk.y = (unsigned)wv[2] | ((unsigned)wv[3] << 16);
        pk.z = (unsigned)wv[4] | ((unsigned)wv[5] << 16);
        pk.w = (unsigned)wv[6] | ((unsigned)wv[7] << 16);
        *reinterpret_cast<uint4*>(outp + widx0) = pk;
    }
}

// out = x + ((x * SE_b) * S^T) via split-bf16 MFMA, LDS-staged x (hi/lo),
// XPAD=524. grid (128, 8), 4 waves (rw=row-half, cw=col-half).
__global__ __launch_bounds__(256, 2) void k_mix(const float* x,
                                                const unsigned short* SEf,
                                                const unsigned short* Sf,
                                                float* out) {
    __shared__ unsigned short xh[32 * XPAD];
    __shared__ unsigned short xl[32 * XPAD];
    __shared__ float Zs[32 * 68];
    const int b = blockIdx.y;
    const int r0 = blockIdx.x * 32;
    const int t = threadIdx.x;
    const int w = t >> 6;
    const int l = t & 63;
    const int lm = l & 15;
    const int lk = (l >> 4) * 8;
    const int rw = w & 1, cw = w >> 1;
    const float* xb = x + (size_t)b * N_ * F_;
    float* outb = out + (size_t)b * N_ * F_;
    const unsigned short* sef = SEf + (size_t)b * 65536;

    // ---- stage: x tile -> split bf16 hi/lo in LDS (coalesced 16B/lane reads) ----
#pragma unroll 4
    for (int it = 0; it < 16; ++it) {
        const int idx = it * 256 + t;
        const int row = idx >> 7, c4 = (idx & 127) * 4;
        const float4 v = *reinterpret_cast<const float4*>(
            xb + (size_t)(r0 + row) * F_ + c4);
        ushort4 hs, ls;
        short hh, ss;
        bf16_split(v.x, hh, ss); hs.x = (unsigned short)hh; ls.x = (unsigned short)ss;
        bf16_split(v.y, hh, ss); hs.y = (unsigned short)hh; ls.y = (unsigned short)ss;
        bf16_split(v.z, hh, ss); hs.z = (unsigned short)hh; ls.z = (unsigned short)ss;
        bf16_split(v.w, hh, ss); hs.w = (unsigned short)hh; ls.w = (unsigned short)ss;
        *reinterpret_cast<ushort4*>(&xh[row * XPAD + c4]) = hs;
        *reinterpret_cast<ushort4*>(&xl[row * XPAD + c4]) = ls;
    }
    __syncthreads();

    // ---- phase 1: Z[32][64] = X_tile * SE ----
    f32x4 ahh0 = {0.f, 0.f, 0.f, 0.f}, alh0 = ahh0, ahl0 = ahh0;
    f32x4 ahh1 = ahh0, alh1 = ahh0, ahl1 = ahh0;
    const unsigned short* xhr = xh + (16 * rw + lm) * XPAD;
    const unsigned short* xlr = xl + (16 * rw + lm) * XPAD;
#pragma unroll 4
    for (int kk = 0; kk < 16; ++kk) {
        const int k0 = kk * 32 + lk;
        const bf16x8 ah = *reinterpret_cast<const bf16x8*>(xhr + k0);
        const bf16x8 al = *reinterpret_cast<const bf16x8*>(xlr + k0);
        const int o0 = (kk * 4 + 2 * cw) * 1024 + l * 8;
        const bf16x8 bh0 = *reinterpret_cast<const bf16x8*>(sef + o0);
        const bf16x8 bl0 = *reinterpret_cast<const bf16x8*>(sef + o0 + 512);
        const bf16x8 bh1 = *reinterpret_cast<const bf16x8*>(sef + o0 + 1024);
        const bf16x8 bl1 = *reinterpret_cast<const bf16x8*>(sef + o0 + 1536);
        ahh0 = __builtin_amdgcn_mfma_f32_16x16x32_bf16(ah, bh0, ahh0, 0, 0, 0);
        alh0 = __builtin_amdgcn_mfma_f32_16x16x32_bf16(al, bh0, alh0, 0, 0, 0);
        ahl0 = __builtin_amdgcn_mfma_f32_16x16x32_bf16(ah, bl0, ahl0, 0, 0, 0);
        ahh1 = __builtin_amdgcn_mfma_f32_16x16x32_bf16(ah, bh1, ahh1, 0, 0, 0);
        alh1 = __builtin_amdgcn_mfma_f32_16x16x32_bf16(al, bh1, alh1, 0, 0, 0);
        ahl1 = __builtin_amdgcn_mfma_f32_16x16x32_bf16(ah, bl1, ahl1, 0, 0, 0);
    }
#pragma unroll
    for (int r = 0; r < 4; ++r) {
        const int zr = (16 * rw + (l >> 4) * 4 + r) * 68 + 32 * cw;
        Zs[zr + lm] = ahh0[r] + alh0[r] + ahl0[r];
        Zs[zr + 16 + lm] = ahh1[r] + alh1[r] + ahl1[r];
    }
    __syncthreads();

    // ---- phase 2: out[32][512] = X + Z * S^T ----
    bf16x8 zh0, zl0, zh1, zl1;
    {
        const float* zrow = &Zs[(16 * rw + lm) * 68];
#pragma unroll
        for (int i = 0; i < 8; ++i) {
            short hh, ss;
            bf16_split(zrow[lk + i], hh, ss);
            zh0[i] = hh; zl0[i] = ss;
            bf16_split(zrow[32 + lk + i], hh, ss);
            zh1[i] = hh; zl1[i] = ss;
        }
    }
    const int lrow0 = 16 * rw + (l >> 4) * 4;
    const int orow0 = r0 + lrow0;
#pragma unroll 2
    for (int j2 = 0; j2 < 16; ++j2) {
        const int ht = cw * 16 + j2;
        const int h0 = ht * 16 + lm;
        f32x4 ca = {0.f, 0.f, 0.f, 0.f};
        f32x4 cb;
#pragma unroll
        for (int r = 0; r < 4; ++r) {
            const int la = (lrow0 + r) * XPAD + h0;
            cb[r] = b2f(xh[la]) + b2f(xl[la]);
        }
        const int fb = ht * 2048 + l * 8;
        const bf16x8 bh0 = *reinterpret_cast<const bf16x8*>(Sf + fb);
        const bf16x8 bl0 = *reinterpret_cast<const bf16x8*>(Sf + fb + 512);
        const bf16x8 bh1 = *reinterpret_cast<const bf16x8*>(Sf + fb + 1024);
        const bf16x8 bl1 = *reinterpret_cast<const bf16x8*>(Sf + fb + 1536);
        ca = __builtin_amdgcn_mfma_f32_16x16x32_bf16(zh0, bh0, ca, 0, 0, 0);
        ca = __builtin_amdgcn_mfma_f32_16x16x32_bf16(zl0, bh0, ca, 0, 0, 0);
        ca = __builtin_amdgcn_mfma_f32_16x16x32_bf16(zh0, bl0, ca, 0, 0, 0);
        cb = __builtin_amdgcn_mfma_f32_16x16x32_bf16(zh1, bh1, cb, 0, 0, 0);
        cb = __builtin_amdgcn_mfma_f32_16x16x32_bf16(zl1, bh1, cb, 0, 0, 0);
        cb = __builtin_amdgcn_mfma_f32_16x16x32_bf16(zh1, bl1, cb, 0, 0, 0);
#pragma unroll
        for (int r = 0; r < 4; ++r)
            outb[(size_t)(orow0 + r) * F_ + h0] = ca[r] + cb[r];
    }
}

extern "C" void kernel_launch(void* const* d_in, const int* in_sizes, int n_in,
                              void* d_out, int out_size, void* d_ws, size_t ws_size,
                              hipStream_t stream) {
    (void)in_sizes; (void)n_in; (void)out_size; (void)ws_size;
    const float* x       = (const float*)d_in[0];
    const float* coeff   = (const float*)d_in[1];
    const float* gate    = (const float*)d_in[2];
    const float* coeff_l = (const float*)d_in[3];
    const float* gate_l  = (const float*)d_in[4];
    const float* comm    = (const float*)d_in[5];
    const float* l       = (const float*)d_in[6];
    const float* r       = (const float*)d_in[7];
    const float* ll      = (const float*)d_in[8];
    const float* rl      = (const float*)d_in[9];

    char* wsb = (char*)d_ws;
    float* GS   = (float*)(wsb);                              // 4096 f       @0
    unsigned short* SEf = (unsigned short*)(wsb + 147456);    // 8*65536 u16  @144K (1MB)
    unsigned short* Sf  = (unsigned short*)(wsb + 1196032);   // 65536 u16    @1168K (128K)
    float* Mws  = (float*)(wsb + 1327104);                    // 8*4096 f     @1296K
    float* CPws = (float*)(wsb + 1458176);                    // 8*4096 f     @1424K
    float* Kws  = (float*)(wsb + 1589248);                    // 8*4096 f     @1552K (ends 1680K)
    float* out = (float*)d_out;

    k_prep<<<dim3(64), dim3(256), 0, stream>>>(l, r, ll, rl, GS, Sf);
    k_pre<<<dim3(8), dim3(256), 0, stream>>>(coeff, gate, coeff_l, gate_l, comm, GS,
                                             Mws, CPws);
    k_inv<<<dim3(8), dim3(64), 0, stream>>>(Mws, Kws);
    k_sepost<<<dim3(8, 8), dim3(256), 0, stream>>>(coeff, coeff_l, l, r, ll, rl,
                                                   Mws, CPws, Kws, SEf);
    k_mix<<<dim3(128, 8), dim3(256), 0, stream>>>(x, SEf, Sf, out);
}

// Round 19
// 112.018 us; speedup vs baseline: 1.1620x; 1.0004x over previous
//
#include <hip/hip_runtime.h>

#define B_ 8
#define N_ 4096
#define F_ 512

typedef __attribute__((ext_vector_type(8))) short bf16x8;
typedef __attribute__((ext_vector_type(4))) float f32x4;

#define XPAD 524   // u16 row stride: 262 dw == 6 mod 32 -> distinct lane banks; 8B-aligned

// S (512 x 64) = [left | right | left_local | right_local], each [512][16] row-major.
__device__ __forceinline__ float Sval(const float* l, const float* r,
                                      const float* ll, const float* rl,
                                      int h, int e) {
    const int m = e >> 4, c = e & 15;
    const float* p = (m == 0) ? l : (m == 1) ? r : (m == 2) ? ll : rl;
    return p[h * 16 + c];
}

__device__ __forceinline__ float qval(const float* coeff, const float* coeff_l,
                                      int b, int j) {
    if (j < 16) return 1.f;
    if (j < 32) return coeff[b * 16 + (j - 16)];
    if (j < 48) return 1.f;
    return coeff_l[b * 16 + (j - 48)];
}

__device__ __forceinline__ float lane_bcast(float v, int lane) {
    return __int_as_float(__builtin_amdgcn_readlane(__float_as_int(v), lane));
}

__device__ __forceinline__ unsigned short bf16_rn(float x) {
    unsigned u = __float_as_uint(x);
    unsigned r = u + 0x7FFFu + ((u >> 16) & 1u);
    return (unsigned short)(r >> 16);
}

// split x ~= hi + lo, both bf16 (error ~2^-17 |x|)
__device__ __forceinline__ void bf16_split(float x, short& hi, short& lo) {
    const unsigned short h = bf16_rn(x);
    const float hf = __uint_as_float(((unsigned)h) << 16);
    const unsigned short s = bf16_rn(x - hf);
    hi = (short)h; lo = (short)s;
}

__device__ __forceinline__ float b2f(unsigned short u) {
    return __uint_as_float(((unsigned)u) << 16);
}

// ---- k_prep: GS row i + S-fragment f2=i for phase-2 B-operand. grid 64.
__global__ __launch_bounds__(256) void k_prep(const float* l, const float* r,
                                              const float* ll, const float* rl,
                                              float* GS, unsigned short* Sf) {
    __shared__ float red[4][64];
    const int i = blockIdx.x;
    const int t = threadIdx.x;
    const int j = t & 63, seg = t >> 6;

    {
        const int ht = i >> 1, eh = i & 1;
        for (int idx = t; idx < 512; idx += 256) {
            const int lx = idx >> 3, ii = idx & 7;
            const int h = ht * 16 + (lx & 15);
            const int e = eh * 32 + ((lx >> 4) & 3) * 8 + ii;
            short hh, ss;
            bf16_split(Sval(l, r, ll, rl, h, e), hh, ss);
            Sf[(i * 2 + 0) * 512 + idx] = (unsigned short)hh;
            Sf[(i * 2 + 1) * 512 + idx] = (unsigned short)ss;
        }
    }

    float acc = 0.f;
    const int h0 = seg * 128;
    for (int h = h0; h < h0 + 128; ++h)
        acc += Sval(l, r, ll, rl, h, i) * Sval(l, r, ll, rl, h, j);
    red[seg][j] = acc;
    __syncthreads();
    if (t < 64) GS[i * 64 + t] = red[0][t] + red[1][t] + red[2][t] + red[3][t];
}

// ---- k_pre: build CP and M = I - 0.5 CQ^T GS CP -> Mws, CPws. 8 blocks.
__global__ __launch_bounds__(256) void k_pre(const float* coeff, const float* gate,
                                             const float* coeff_l, const float* gate_l,
                                             const float* comm, const float* GS,
                                             float* Mws, float* CPws) {
    __shared__ float GST[4096];
    __shared__ float CPs[4096];
    __shared__ float ABs[2048];
    __shared__ float u1s[32], u2s[32];

    const int b = blockIdx.x, t = threadIdx.x;
    const int tx = t & 15, ty = t >> 4;
    const float g = gate[b], gl = gate_l[b];
    const float cs = comm[b] / 12.0f;

    if (t < 32) {
        u1s[t] = (t < 16) ? g * coeff[b * 16 + t] : -g;
        u2s[t] = (t < 16) ? gl * coeff_l[b * 16 + t] : -gl;
    }
    for (int idx = t; idx < 4096; idx += 256) {
        const int i = idx & 63, e = idx >> 6;
        GST[idx] = -0.5f * qval(coeff, coeff_l, b, i) * GS[(i ^ 16) * 64 + e];
    }
    __syncthreads();

    for (int idx = t; idx < 2048; idx += 256) {
        const int which = idx >> 10;
        const int i = (idx >> 5) & 31, j = idx & 31;
        float val;
        if (which == 0) {
            const int v2i = (i < 16) ? 48 + i : 16 + i;
            const float v2sc = (i < 16) ? 1.f : coeff_l[b * 16 + (i - 16)];
            val = v2sc * u1s[j] * GS[v2i * 64 + j];
        } else {
            const int v1i = (i < 16) ? 16 + i : i - 16;
            const float v1sc = (i < 16) ? 1.f : coeff[b * 16 + (i - 16)];
            val = v1sc * u2s[j] * GS[v1i * 64 + 32 + j];
        }
        ABs[idx] = val;
    }
    __syncthreads();

    for (int idx = t; idx < 4096; idx += 256) {
        const int e = idx >> 6, j = idx & 63;
        float val = 0.f;
        if (j < 32) {
            if (e == j) val += 0.5f * u1s[j];
            if (e >= 32) val += cs * u2s[e - 32] * ABs[(e - 32) * 32 + j];
        } else {
            const int jp = j - 32;
            if (e == 32 + jp) val += 0.5f * u2s[jp];
            if (e < 32) val -= cs * u1s[e] * ABs[1024 + e * 32 + jp];
        }
        CPs[idx] = val;
        CPws[b * 4096 + idx] = val;
    }
    __syncthreads();

    {
        const int i0 = ty * 4, m0 = tx * 4;
        float acc[4][4];
#pragma unroll
        for (int i = 0; i < 4; ++i)
#pragma unroll
            for (int j = 0; j < 4; ++j) acc[i][j] = 0.f;
        for (int e = 0; e < 64; ++e) {
            const float4 av = *reinterpret_cast<const float4*>(&GST[e * 64 + i0]);
            const float4 bv = *reinterpret_cast<const float4*>(&CPs[e * 64 + m0]);
            const float a[4] = {av.x, av.y, av.z, av.w};
            const float bb[4] = {bv.x, bv.y, bv.z, bv.w};
#pragma unroll
            for (int i = 0; i < 4; ++i)
#pragma unroll
                for (int j = 0; j < 4; ++j) acc[i][j] += a[i] * bb[j];
        }
#pragma unroll
        for (int i = 0; i < 4; ++i) {
            float4 o;
            o.x = acc[i][0] + (((i0 + i) == (m0 + 0)) ? 1.f : 0.f);
            o.y = acc[i][1] + (((i0 + i) == (m0 + 1)) ? 1.f : 0.f);
            o.z = acc[i][2] + (((i0 + i) == (m0 + 2)) ? 1.f : 0.f);
            o.w = acc[i][3] + (((i0 + i) == (m0 + 3)) ? 1.f : 0.f);
            *reinterpret_cast<float4*>(&Mws[b * 4096 + (i0 + i) * 64 + m0]) = o;
        }
    }
}

// ---- k_inv: BLOCKED single-wave register Gauss-Jordan, 8 macro-steps, 0 barriers.
#define DO64(M, K) \
    M(0, K) M(1, K) M(2, K) M(3, K) M(4, K) M(5, K) M(6, K) M(7, K) \
    M(8, K) M(9, K) M(10, K) M(11, K) M(12, K) M(13, K) M(14, K) M(15, K) \
    M(16, K) M(17, K) M(18, K) M(19, K) M(20, K) M(21, K) M(22, K) M(23, K) \
    M(24, K) M(25, K) M(26, K) M(27, K) M(28, K) M(29, K) M(30, K) M(31, K) \
    M(32, K) M(33, K) M(34, K) M(35, K) M(36, K) M(37, K) M(38, K) M(39, K) \
    M(40, K) M(41, K) M(42, K) M(43, K) M(44, K) M(45, K) M(46, K) M(47, K) \
    M(48, K) M(49, K) M(50, K) M(51, K) M(52, K) M(53, K) M(54, K) M(55, K) \
    M(56, K) M(57, K) M(58, K) M(59, K) M(60, K) M(61, K) M(62, K) M(63, K)

#define GJ_LOAD(RR, K) a[RR] = Mws[base + (RR)*64 + t];
#define GJ_STORE(RR, K) Kws[base + (RR)*64 + t] = a[RR];

#define INV_SNAP(RR, G) if (ing) Msnap[(RR) * 8 + gl] = a[RR];

#define IGU(I, G, J) \
    if ((I) != (J)) { \
        const float f_ = lane_bcast(a[(G)*8 + (I)], (G)*8 + (J)); \
        a[(G)*8 + (I)] = __builtin_fmaf(-f_, akp[J], a[(G)*8 + (I)]); \
    }

#define IGS(G, J) { \
    const float dk = lane_bcast(a[(G)*8 + (J)], (G)*8 + (J)); \
    const float pinv = 1.0f / dk; \
    a[(G)*8 + (J)] = (t == ((G)*8 + (J))) ? pinv : a[(G)*8 + (J)] * pinv; \
    akp[J] = a[(G)*8 + (J)] + ((t == ((G)*8 + (J))) ? 1.0f : 0.0f); \
    IGU(0, G, J) IGU(1, G, J) IGU(2, G, J) IGU(3, G, J) \
    IGU(4, G, J) IGU(5, G, J) IGU(6, G, J) IGU(7, G, J) }

#define TRL(RR, G) \
    if (((RR) >> 3) != (G)) { \
        const float4 m0 = *reinterpret_cast<const float4*>(&Msnap[(RR) * 8]); \
        const float4 m1 = *reinterpret_cast<const float4*>(&Msnap[(RR) * 8 + 4]); \
        a[RR] = __builtin_fmaf(-m0.x, akp[0], a[RR]); \
        a[RR] = __builtin_fmaf(-m0.y, akp[1], a[RR]); \
        a[RR] = __builtin_fmaf(-m0.z, akp[2], a[RR]); \
        a[RR] = __builtin_fmaf(-m0.w, akp[3], a[RR]); \
        a[RR] = __builtin_fmaf(-m1.x, akp[4], a[RR]); \
        a[RR] = __builtin_fmaf(-m1.y, akp[5], a[RR]); \
        a[RR] = __builtin_fmaf(-m1.z, akp[6], a[RR]); \
        a[RR] = __builtin_fmaf(-m1.w, akp[7], a[RR]); \
    }

#define MACRO_STEP(G) { \
    float akp[8]; \
    const bool ing = ((t >> 3) == (G)); \
    DO64(INV_SNAP, G) \
    IGS(G, 0) IGS(G, 1) IGS(G, 2) IGS(G, 3) \
    IGS(G, 4) IGS(G, 5) IGS(G, 6) IGS(G, 7) \
    DO64(TRL, G) }

__global__ __launch_bounds__(64, 1) void k_inv(const float* Mws, float* Kws) {
    __shared__ float Msnap[512];
    const int b = blockIdx.x, t = threadIdx.x;  // lane t owns column t
    const int base = b * 4096;
    const int gl = t & 7;
    float a[64];
    DO64(GJ_LOAD, 0)
    MACRO_STEP(0) MACRO_STEP(1) MACRO_STEP(2) MACRO_STEP(3)
    MACRO_STEP(4) MACRO_STEP(5) MACRO_STEP(6) MACRO_STEP(7)
    DO64(GJ_STORE, 0)
}

// ---- k_sepost: fused Newton+E (per-b, redundantly per hc) and SE-chunk emission.
// grid (hc=8, b=8). LDS flat 80KB, phase-overlaid.
__global__ __launch_bounds__(256) void k_sepost(const float* coeff, const float* coeff_l,
                                                const float* l, const float* r,
                                                const float* ll, const float* rl,
                                                const float* Mws, const float* CPws,
                                                const float* Kws, unsigned short* SEf) {
    __shared__ float smem[20480];
    float* Ms  = smem;
    float* CPs = smem + 4096;
    float* Ks  = smem + 8192;
    float* Tds = smem + 12288;
    float* Tas = smem + 16384;
    float* Es  = smem;          // phase B
    float* Ss  = smem + 4096;   // phase B, stride 66 (4224 floats)
    float* SEs = smem + 8320;   // phase C, stride 65 (4160 floats)

    const int b = blockIdx.y, hc = blockIdx.x, t = threadIdx.x;
    const int tx = t & 15, ty = t >> 4;

    for (int idx = t; idx < 4096; idx += 256) {
        Ms[idx] = Mws[b * 4096 + idx];
        CPs[idx] = CPws[b * 4096 + idx];
        Ks[idx] = Kws[b * 4096 + idx];
    }
    __syncthreads();

    // Td = CP*K ; Ta = M*K
    {
        const int i0 = ty * 4, j0 = tx * 4;
        float accd[4][4], acca[4][4];
#pragma unroll
        for (int i = 0; i < 4; ++i)
#pragma unroll
            for (int j = 0; j < 4; ++j) { accd[i][j] = 0.f; acca[i][j] = 0.f; }
        for (int q = 0; q < 64; ++q) {
            const float4 bv = *reinterpret_cast<const float4*>(&Ks[q * 64 + j0]);
            const float bb[4] = {bv.x, bv.y, bv.z, bv.w};
            float ad[4], aa[4];
#pragma unroll
            for (int i = 0; i < 4; ++i) {
                ad[i] = CPs[(i0 + i) * 64 + q];
                aa[i] = Ms[(i0 + i) * 64 + q];
            }
#pragma unroll
            for (int i = 0; i < 4; ++i)
#pragma unroll
                for (int j = 0; j < 4; ++j) {
                    accd[i][j] += ad[i] * bb[j];
                    acca[i][j] += aa[i] * bb[j];
                }
        }
        __syncthreads();
#pragma unroll
        for (int i = 0; i < 4; ++i)
#pragma unroll
            for (int j = 0; j < 4; ++j) {
                Tds[(i0 + i) * 64 + j0 + j] = accd[i][j];
                Tas[(i0 + i) * 64 + j0 + j] = acca[i][j];
            }
    }
    __syncthreads();

    // E[e][c^16] = q(c)*(2Td - Td*Ta)[e][c] -> R0 ; Ss chunk -> R1+
    {
        const int e0 = ty * 4, c0 = tx * 4;
        float acc[4][4];
#pragma unroll
        for (int i = 0; i < 4; ++i)
#pragma unroll
            for (int j = 0; j < 4; ++j) acc[i][j] = 0.f;
        for (int q = 0; q < 64; ++q) {
            const float4 bv = *reinterpret_cast<const float4*>(&Tas[q * 64 + c0]);
            const float bb[4] = {bv.x, bv.y, bv.z, bv.w};
            float a[4];
#pragma unroll
            for (int i = 0; i < 4; ++i) a[i] = Tds[(e0 + i) * 64 + q];
#pragma unroll
            for (int i = 0; i < 4; ++i)
#pragma unroll
                for (int j = 0; j < 4; ++j) acc[i][j] += a[i] * bb[j];
        }
        float qv[4];
#pragma unroll
        for (int j = 0; j < 4; ++j) qv[j] = qval(coeff, coeff_l, b, c0 + j);
#pragma unroll
        for (int i = 0; i < 4; ++i) {
            float4 o;
            o.x = qv[0] * (2.f * Tds[(e0 + i) * 64 + c0 + 0] - acc[i][0]);
            o.y = qv[1] * (2.f * Tds[(e0 + i) * 64 + c0 + 1] - acc[i][1]);
            o.z = qv[2] * (2.f * Tds[(e0 + i) * 64 + c0 + 2] - acc[i][2]);
            o.w = qv[3] * (2.f * Tds[(e0 + i) * 64 + c0 + 3] - acc[i][3]);
            *reinterpret_cast<float4*>(&Es[(e0 + i) * 64 + (c0 ^ 16)]) = o;
        }
        for (int idx = t; idx < 4096; idx += 256) {
            const int hl_ = idx >> 6, e = idx & 63;
            Ss[hl_ * 66 + e] = Sval(l, r, ll, rl, hc * 64 + hl_, e);
        }
    }
    __syncthreads();

    // SE rows: SEs[h][m] = sum_e Ss[h][e]*Es[e][m]
    {
        const int h = t >> 2;
        const int mg = (t & 3) * 16;
        float acc[16];
#pragma unroll
        for (int q = 0; q < 16; ++q) acc[q] = 0.f;
#pragma unroll 4
        for (int e = 0; e < 64; ++e) {
            const float s = Ss[h * 66 + e];
            const float* Er = Es + e * 64 + mg;
#pragma unroll
            for (int q = 0; q < 16; ++q) acc[q] += s * Er[q];
        }
        __syncthreads();
#pragma unroll
        for (int q = 0; q < 16; ++q) SEs[h * 65 + mg + q] = acc[q];
    }
    __syncthreads();

    unsigned short* outp = SEf + (size_t)b * 65536 + hc * 8192;
#pragma unroll
    for (int it = 0; it < 4; ++it) {
        const int widx0 = it * 2048 + t * 8;
        const int fl = widx0 >> 10;
        const int hl = (widx0 >> 9) & 1;
        const int lx = (widx0 >> 3) & 63;
        const int m = (fl & 3) * 16 + (lx & 15);
        const int hb = (fl >> 2) * 32 + ((lx >> 4) & 3) * 8;
        unsigned short wv[8];
#pragma unroll
        for (int i = 0; i < 8; ++i) {
            short hh, ss;
            bf16_split(SEs[(hb + i) * 65 + m], hh, ss);
            wv[i] = hl ? (unsigned short)ss : (unsigned short)hh;
        }
        uint4 pk;
        pk.x = (unsigned)wv[0] | ((unsigned)wv[1] << 16);
        pk.y = (unsigned)wv[2] | ((unsigned)wv[3] << 16);
        pk.z = (unsigned)wv[4] | ((unsigned)wv[5] << 16);
        pk.w = (unsigned)wv[6] | ((unsigned)wv[7] << 16);
        *reinterpret_cast<uint4*>(outp + widx0) = pk;
    }
}

// out = x + ((x * SE_b) * S^T) via split-bf16 MFMA, LDS-staged x (hi/lo).
// 16-ROW TILES with n-split waves (no k-split, no LDS reduce — unlike R8):
// phase 1: wave w owns Z-cols 16w..16w+15 (one n-tile, 3 MFMA/kk);
// phase 2: wave w owns output cols 128w..128w+127.
// LDS 37888B -> 4 blocks/CU (R13's 32-row/75776B capped at 2; occupancy 18%).
// grid (256, 8) = 2048 blocks.
__global__ __launch_bounds__(256, 4) void k_mix(const float* x,
                                                const unsigned short* SEf,
                                                const unsigned short* Sf,
                                                float* out) {
    __shared__ unsigned short xh[16 * XPAD];
    __shared__ unsigned short xl[16 * XPAD];
    __shared__ float Zs[16 * 68];
    const int b = blockIdx.y;
    const int r0 = blockIdx.x * 16;
    const int t = threadIdx.x;
    const int w = t >> 6;
    const int l = t & 63;
    const int lm = l & 15;
    const int lk = (l >> 4) * 8;
    const float* xb = x + (size_t)b * N_ * F_;
    float* outb = out + (size_t)b * N_ * F_;
    const unsigned short* sef = SEf + (size_t)b * 65536;

    // ---- stage: 16x512 x tile -> split bf16 hi/lo in LDS ----
#pragma unroll 4
    for (int it = 0; it < 8; ++it) {
        const int idx = it * 256 + t;
        const int row = idx >> 7, c4 = (idx & 127) * 4;
        const float4 v = *reinterpret_cast<const float4*>(
            xb + (size_t)(r0 + row) * F_ + c4);
        ushort4 hs, ls;
        short hh, ss;
        bf16_split(v.x, hh, ss); hs.x = (unsigned short)hh; ls.x = (unsigned short)ss;
        bf16_split(v.y, hh, ss); hs.y = (unsigned short)hh; ls.y = (unsigned short)ss;
        bf16_split(v.z, hh, ss); hs.z = (unsigned short)hh; ls.z = (unsigned short)ss;
        bf16_split(v.w, hh, ss); hs.w = (unsigned short)hh; ls.w = (unsigned short)ss;
        *reinterpret_cast<ushort4*>(&xh[row * XPAD + c4]) = hs;
        *reinterpret_cast<ushort4*>(&xl[row * XPAD + c4]) = ls;
    }
    __syncthreads();

    // ---- phase 1: Z[16][64] = X_tile * SE ; wave w -> n-tile w ----
    f32x4 ahh = {0.f, 0.f, 0.f, 0.f}, alh = ahh, ahl = ahh;
    const unsigned short* xhr = xh + lm * XPAD;
    const unsigned short* xlr = xl + lm * XPAD;
#pragma unroll 4
    for (int kk = 0; kk < 16; ++kk) {
        const int k0 = kk * 32 + lk;
        const bf16x8 ah = *reinterpret_cast<const bf16x8*>(xhr + k0);
        const bf16x8 al = *reinterpret_cast<const bf16x8*>(xlr + k0);
        const int o0 = (kk * 4 + w) * 1024 + l * 8;
        const bf16x8 bh = *reinterpret_cast<const bf16x8*>(sef + o0);
        const bf16x8 bl = *reinterpret_cast<const bf16x8*>(sef + o0 + 512);
        ahh = __builtin_amdgcn_mfma_f32_16x16x32_bf16(ah, bh, ahh, 0, 0, 0);
        alh = __builtin_amdgcn_mfma_f32_16x16x32_bf16(al, bh, alh, 0, 0, 0);
        ahl = __builtin_amdgcn_mfma_f32_16x16x32_bf16(ah, bl, ahl, 0, 0, 0);
    }
#pragma unroll
    for (int r = 0; r < 4; ++r) {
        const int zr = ((l >> 4) * 4 + r) * 68 + w * 16;
        Zs[zr + lm] = ahh[r] + alh[r] + ahl[r];
    }
    __syncthreads();

    // ---- phase 2: out[16][512] = X + Z * S^T ; wave w -> cols 128w..128w+127 ----
    bf16x8 zh0, zl0, zh1, zl1;
    {
        const float* zrow = &Zs[lm * 68];
#pragma unroll
        for (int i = 0; i < 8; ++i) {
            short hh, ss;
            bf16_split(zrow[lk + i], hh, ss);
            zh0[i] = hh; zl0[i] = ss;
            bf16_split(zrow[32 + lk + i], hh, ss);
            zh1[i] = hh; zl1[i] = ss;
        }
    }
    const int lrow0 = (l >> 4) * 4;
    const int orow0 = r0 + lrow0;
#pragma unroll 2
    for (int j2 = 0; j2 < 8; ++j2) {
        const int ht = w * 8 + j2;
        const int h0 = ht * 16 + lm;
        f32x4 ca = {0.f, 0.f, 0.f, 0.f};
        f32x4 cb;
#pragma unroll
        for (int r = 0; r < 4; ++r) {
            const int la = (lrow0 + r) * XPAD + h0;
            cb[r] = b2f(xh[la]) + b2f(xl[la]);
        }
        const int fb = ht * 2048 + l * 8;
        const bf16x8 bh0 = *reinterpret_cast<const bf16x8*>(Sf + fb);
        const bf16x8 bl0 = *reinterpret_cast<const bf16x8*>(Sf + fb + 512);
        const bf16x8 bh1 = *reinterpret_cast<const bf16x8*>(Sf + fb + 1024);
        const bf16x8 bl1 = *reinterpret_cast<const bf16x8*>(Sf + fb + 1536);
        ca = __builtin_amdgcn_mfma_f32_16x16x32_bf16(zh0, bh0, ca, 0, 0, 0);
        ca = __builtin_amdgcn_mfma_f32_16x16x32_bf16(zl0, bh0, ca, 0, 0, 0);
        ca = __builtin_amdgcn_mfma_f32_16x16x32_bf16(zh0, bl0, ca, 0, 0, 0);
        cb = __builtin_amdgcn_mfma_f32_16x16x32_bf16(zh1, bh1, cb, 0, 0, 0);
        cb = __builtin_amdgcn_mfma_f32_16x16x32_bf16(zl1, bh1, cb, 0, 0, 0);
        cb = __builtin_amdgcn_mfma_f32_16x16x32_bf16(zh1, bl1, cb, 0, 0, 0);
#pragma unroll
        for (int r = 0; r < 4; ++r)
            outb[(size_t)(orow0 + r) * F_ + h0] = ca[r] + cb[r];
    }
}

extern "C" void kernel_launch(void* const* d_in, const int* in_sizes, int n_in,
                              void* d_out, int out_size, void* d_ws, size_t ws_size,
                              hipStream_t stream) {
    (void)in_sizes; (void)n_in; (void)out_size; (void)ws_size;
    const float* x       = (const float*)d_in[0];
    const float* coeff   = (const float*)d_in[1];
    const float* gate    = (const float*)d_in[2];
    const float* coeff_l = (const float*)d_in[3];
    const float* gate_l  = (const float*)d_in[4];
    const float* comm    = (const float*)d_in[5];
    const float* l       = (const float*)d_in[6];
    const float* r       = (const float*)d_in[7];
    const float* ll      = (const float*)d_in[8];
    const float* rl      = (const float*)d_in[9];

    char* wsb = (char*)d_ws;
    float* GS   = (float*)(wsb);                              // 4096 f       @0
    unsigned short* SEf = (unsigned short*)(wsb + 147456);    // 8*65536 u16  @144K (1MB)
    unsigned short* Sf  = (unsigned short*)(wsb + 1196032);   // 65536 u16    @1168K (128K)
    float* Mws  = (float*)(wsb + 1327104);                    // 8*4096 f     @1296K
    float* CPws = (float*)(wsb + 1458176);                    // 8*4096 f     @1424K
    float* Kws  = (float*)(wsb + 1589248);                    // 8*4096 f     @1552K (ends 1680K)
    float* out = (float*)d_out;

    k_prep<<<dim3(64), dim3(256), 0, stream>>>(l, r, ll, rl, GS, Sf);
    k_pre<<<dim3(8), dim3(256), 0, stream>>>(coeff, gate, coeff_l, gate_l, comm, GS,
                                             Mws, CPws);
    k_inv<<<dim3(8), dim3(64), 0, stream>>>(Mws, Kws);
    k_sepost<<<dim3(8, 8), dim3(256), 0, stream>>>(coeff, coeff_l, l, r, ll, rl,
                                                   Mws, CPws, Kws, SEf);
    k_mix<<<dim3(256, 8), dim3(256), 0, stream>>>(x, SEf, Sf, out);
}

// Round 20
// 107.266 us; speedup vs baseline: 1.2134x; 1.0443x over previous
//
#include <hip/hip_runtime.h>

#define B_ 8
#define N_ 4096
#define F_ 512

typedef __attribute__((ext_vector_type(8))) short bf16x8;
typedef __attribute__((ext_vector_type(4))) float f32x4;

#define XPAD 524   // u16 row stride: 262 dw == 6 mod 32 -> distinct lane banks; 8B-aligned

// S (512 x 64) = [left | right | left_local | right_local], each [512][16] row-major.
__device__ __forceinline__ float Sval(const float* l, const float* r,
                                      const float* ll, const float* rl,
                                      int h, int e) {
    const int m = e >> 4, c = e & 15;
    const float* p = (m == 0) ? l : (m == 1) ? r : (m == 2) ? ll : rl;
    return p[h * 16 + c];
}

__device__ __forceinline__ float qval(const float* coeff, const float* coeff_l,
                                      int b, int j) {
    if (j < 16) return 1.f;
    if (j < 32) return coeff[b * 16 + (j - 16)];
    if (j < 48) return 1.f;
    return coeff_l[b * 16 + (j - 48)];
}

__device__ __forceinline__ float lane_bcast(float v, int lane) {
    return __int_as_float(__builtin_amdgcn_readlane(__float_as_int(v), lane));
}

__device__ __forceinline__ unsigned short bf16_rn(float x) {
    unsigned u = __float_as_uint(x);
    unsigned r = u + 0x7FFFu + ((u >> 16) & 1u);
    return (unsigned short)(r >> 16);
}

// split x ~= hi + lo, both bf16 (error ~2^-17 |x|)
__device__ __forceinline__ void bf16_split(float x, short& hi, short& lo) {
    const unsigned short h = bf16_rn(x);
    const float hf = __uint_as_float(((unsigned)h) << 16);
    const unsigned short s = bf16_rn(x - hf);
    hi = (short)h; lo = (short)s;
}

__device__ __forceinline__ float b2f(unsigned short u) {
    return __uint_as_float(((unsigned)u) << 16);
}

// ---- k_prep: GS row i + S-fragment f2=i for phase-2 B-operand. grid 64.
__global__ __launch_bounds__(256) void k_prep(const float* l, const float* r,
                                              const float* ll, const float* rl,
                                              float* GS, unsigned short* Sf) {
    __shared__ float red[4][64];
    const int i = blockIdx.x;
    const int t = threadIdx.x;
    const int j = t & 63, seg = t >> 6;

    {
        const int ht = i >> 1, eh = i & 1;
        for (int idx = t; idx < 512; idx += 256) {
            const int lx = idx >> 3, ii = idx & 7;
            const int h = ht * 16 + (lx & 15);
            const int e = eh * 32 + ((lx >> 4) & 3) * 8 + ii;
            short hh, ss;
            bf16_split(Sval(l, r, ll, rl, h, e), hh, ss);
            Sf[(i * 2 + 0) * 512 + idx] = (unsigned short)hh;
            Sf[(i * 2 + 1) * 512 + idx] = (unsigned short)ss;
        }
    }

    float acc = 0.f;
    const int h0 = seg * 128;
    for (int h = h0; h < h0 + 128; ++h)
        acc += Sval(l, r, ll, rl, h, i) * Sval(l, r, ll, rl, h, j);
    red[seg][j] = acc;
    __syncthreads();
    if (t < 64) GS[i * 64 + t] = red[0][t] + red[1][t] + red[2][t] + red[3][t];
}

// ---- k_pre: build CP and M = I - 0.5 CQ^T GS CP -> Mws, CPws. 8 blocks.
__global__ __launch_bounds__(256) void k_pre(const float* coeff, const float* gate,
                                             const float* coeff_l, const float* gate_l,
                                             const float* comm, const float* GS,
                                             float* Mws, float* CPws) {
    __shared__ float GST[4096];
    __shared__ float CPs[4096];
    __shared__ float ABs[2048];
    __shared__ float u1s[32], u2s[32];

    const int b = blockIdx.x, t = threadIdx.x;
    const int tx = t & 15, ty = t >> 4;
    const float g = gate[b], gl = gate_l[b];
    const float cs = comm[b] / 12.0f;

    if (t < 32) {
        u1s[t] = (t < 16) ? g * coeff[b * 16 + t] : -g;
        u2s[t] = (t < 16) ? gl * coeff_l[b * 16 + t] : -gl;
    }
    for (int idx = t; idx < 4096; idx += 256) {
        const int i = idx & 63, e = idx >> 6;
        GST[idx] = -0.5f * qval(coeff, coeff_l, b, i) * GS[(i ^ 16) * 64 + e];
    }
    __syncthreads();

    for (int idx = t; idx < 2048; idx += 256) {
        const int which = idx >> 10;
        const int i = (idx >> 5) & 31, j = idx & 31;
        float val;
        if (which == 0) {
            const int v2i = (i < 16) ? 48 + i : 16 + i;
            const float v2sc = (i < 16) ? 1.f : coeff_l[b * 16 + (i - 16)];
            val = v2sc * u1s[j] * GS[v2i * 64 + j];
        } else {
            const int v1i = (i < 16) ? 16 + i : i - 16;
            const float v1sc = (i < 16) ? 1.f : coeff[b * 16 + (i - 16)];
            val = v1sc * u2s[j] * GS[v1i * 64 + 32 + j];
        }
        ABs[idx] = val;
    }
    __syncthreads();

    for (int idx = t; idx < 4096; idx += 256) {
        const int e = idx >> 6, j = idx & 63;
        float val = 0.f;
        if (j < 32) {
            if (e == j) val += 0.5f * u1s[j];
            if (e >= 32) val += cs * u2s[e - 32] * ABs[(e - 32) * 32 + j];
        } else {
            const int jp = j - 32;
            if (e == 32 + jp) val += 0.5f * u2s[jp];
            if (e < 32) val -= cs * u1s[e] * ABs[1024 + e * 32 + jp];
        }
        CPs[idx] = val;
        CPws[b * 4096 + idx] = val;
    }
    __syncthreads();

    {
        const int i0 = ty * 4, m0 = tx * 4;
        float acc[4][4];
#pragma unroll
        for (int i = 0; i < 4; ++i)
#pragma unroll
            for (int j = 0; j < 4; ++j) acc[i][j] = 0.f;
        for (int e = 0; e < 64; ++e) {
            const float4 av = *reinterpret_cast<const float4*>(&GST[e * 64 + i0]);
            const float4 bv = *reinterpret_cast<const float4*>(&CPs[e * 64 + m0]);
            const float a[4] = {av.x, av.y, av.z, av.w};
            const float bb[4] = {bv.x, bv.y, bv.z, bv.w};
#pragma unroll
            for (int i = 0; i < 4; ++i)
#pragma unroll
                for (int j = 0; j < 4; ++j) acc[i][j] += a[i] * bb[j];
        }
#pragma unroll
        for (int i = 0; i < 4; ++i) {
            float4 o;
            o.x = acc[i][0] + (((i0 + i) == (m0 + 0)) ? 1.f : 0.f);
            o.y = acc[i][1] + (((i0 + i) == (m0 + 1)) ? 1.f : 0.f);
            o.z = acc[i][2] + (((i0 + i) == (m0 + 2)) ? 1.f : 0.f);
            o.w = acc[i][3] + (((i0 + i) == (m0 + 3)) ? 1.f : 0.f);
            *reinterpret_cast<float4*>(&Mws[b * 4096 + (i0 + i) * 64 + m0]) = o;
        }
    }
}

// ---- k_inv: BLOCKED single-wave register Gauss-Jordan, 8 macro-steps, 0 barriers.
#define DO64(M, K) \
    M(0, K) M(1, K) M(2, K) M(3, K) M(4, K) M(5, K) M(6, K) M(7, K) \
    M(8, K) M(9, K) M(10, K) M(11, K) M(12, K) M(13, K) M(14, K) M(15, K) \
    M(16, K) M(17, K) M(18, K) M(19, K) M(20, K) M(21, K) M(22, K) M(23, K) \
    M(24, K) M(25, K) M(26, K) M(27, K) M(28, K) M(29, K) M(30, K) M(31, K) \
    M(32, K) M(33, K) M(34, K) M(35, K) M(36, K) M(37, K) M(38, K) M(39, K) \
    M(40, K) M(41, K) M(42, K) M(43, K) M(44, K) M(45, K) M(46, K) M(47, K) \
    M(48, K) M(49, K) M(50, K) M(51, K) M(52, K) M(53, K) M(54, K) M(55, K) \
    M(56, K) M(57, K) M(58, K) M(59, K) M(60, K) M(61, K) M(62, K) M(63, K)

#define GJ_LOAD(RR, K) a[RR] = Mws[base + (RR)*64 + t];
#define GJ_STORE(RR, K) Kws[base + (RR)*64 + t] = a[RR];

#define INV_SNAP(RR, G) if (ing) Msnap[(RR) * 8 + gl] = a[RR];

#define IGU(I, G, J) \
    if ((I) != (J)) { \
        const float f_ = lane_bcast(a[(G)*8 + (I)], (G)*8 + (J)); \
        a[(G)*8 + (I)] = __builtin_fmaf(-f_, akp[J], a[(G)*8 + (I)]); \
    }

#define IGS(G, J) { \
    const float dk = lane_bcast(a[(G)*8 + (J)], (G)*8 + (J)); \
    const float pinv = 1.0f / dk; \
    a[(G)*8 + (J)] = (t == ((G)*8 + (J))) ? pinv : a[(G)*8 + (J)] * pinv; \
    akp[J] = a[(G)*8 + (J)] + ((t == ((G)*8 + (J))) ? 1.0f : 0.0f); \
    IGU(0, G, J) IGU(1, G, J) IGU(2, G, J) IGU(3, G, J) \
    IGU(4, G, J) IGU(5, G, J) IGU(6, G, J) IGU(7, G, J) }

#define TRL(RR, G) \
    if (((RR) >> 3) != (G)) { \
        const float4 m0 = *reinterpret_cast<const float4*>(&Msnap[(RR) * 8]); \
        const float4 m1 = *reinterpret_cast<const float4*>(&Msnap[(RR) * 8 + 4]); \
        a[RR] = __builtin_fmaf(-m0.x, akp[0], a[RR]); \
        a[RR] = __builtin_fmaf(-m0.y, akp[1], a[RR]); \
        a[RR] = __builtin_fmaf(-m0.z, akp[2], a[RR]); \
        a[RR] = __builtin_fmaf(-m0.w, akp[3], a[RR]); \
        a[RR] = __builtin_fmaf(-m1.x, akp[4], a[RR]); \
        a[RR] = __builtin_fmaf(-m1.y, akp[5], a[RR]); \
        a[RR] = __builtin_fmaf(-m1.z, akp[6], a[RR]); \
        a[RR] = __builtin_fmaf(-m1.w, akp[7], a[RR]); \
    }

#define MACRO_STEP(G) { \
    float akp[8]; \
    const bool ing = ((t >> 3) == (G)); \
    DO64(INV_SNAP, G) \
    IGS(G, 0) IGS(G, 1) IGS(G, 2) IGS(G, 3) \
    IGS(G, 4) IGS(G, 5) IGS(G, 6) IGS(G, 7) \
    DO64(TRL, G) }

__global__ __launch_bounds__(64, 1) void k_inv(const float* Mws, float* Kws) {
    __shared__ float Msnap[512];
    const int b = blockIdx.x, t = threadIdx.x;  // lane t owns column t
    const int base = b * 4096;
    const int gl = t & 7;
    float a[64];
    DO64(GJ_LOAD, 0)
    MACRO_STEP(0) MACRO_STEP(1) MACRO_STEP(2) MACRO_STEP(3)
    MACRO_STEP(4) MACRO_STEP(5) MACRO_STEP(6) MACRO_STEP(7)
    DO64(GJ_STORE, 0)
}

// ---- k_sepost: E = q ⊙ (CP*K) (Newton DROPPED: fp32 blocked GJ on the
// well-conditioned M (eig 1±iw/2) gives K rel-err ~1e-5 -> E absmax impact
// ~1e-4, two orders below the bf16-split error 0.0156 and three below the
// 0.11 threshold) + SE-chunk + fragment emission. grid (hc=8, b=8).
// LDS 49920B phase-overlaid: A: CPs@0 | Ks@4224 | Es@8384 ;
// B (CPs/Ks dead): Ss@0 (stride 66) | SEs@4224 (stride 65) | Es live.
__global__ __launch_bounds__(256) void k_sepost(const float* coeff, const float* coeff_l,
                                                const float* l, const float* r,
                                                const float* ll, const float* rl,
                                                const float* CPws, const float* Kws,
                                                unsigned short* SEf) {
    __shared__ float smem[12480];
    float* CPs = smem;          // [0,4096)
    float* Ks  = smem + 4224;   // [4224,8320)
    float* Es  = smem + 8384;   // [8384,12480)  live to end
    float* Ss  = smem;          // phase B [0,4224)
    float* SEs = smem + 4224;   // phase B [4224,8384)

    const int b = blockIdx.y, hc = blockIdx.x, t = threadIdx.x;
    const int tx = t & 15, ty = t >> 4;

    for (int idx = t; idx < 4096; idx += 256) {
        CPs[idx] = CPws[b * 4096 + idx];
        Ks[idx] = Kws[b * 4096 + idx];
    }
    __syncthreads();

    // Td = CP*K in regs -> E[e][(c)^16] = q(c)*Td[e][c] straight to Es
    {
        const int e0 = ty * 4, c0 = tx * 4;
        float accd[4][4];
#pragma unroll
        for (int i = 0; i < 4; ++i)
#pragma unroll
            for (int j = 0; j < 4; ++j) accd[i][j] = 0.f;
        for (int q = 0; q < 64; ++q) {
            const float4 bv = *reinterpret_cast<const float4*>(&Ks[q * 64 + c0]);
            const float bb[4] = {bv.x, bv.y, bv.z, bv.w};
            float ad[4];
#pragma unroll
            for (int i = 0; i < 4; ++i) ad[i] = CPs[(e0 + i) * 64 + q];
#pragma unroll
            for (int i = 0; i < 4; ++i)
#pragma unroll
                for (int j = 0; j < 4; ++j) accd[i][j] += ad[i] * bb[j];
        }
        float qv[4];
#pragma unroll
        for (int j = 0; j < 4; ++j) qv[j] = qval(coeff, coeff_l, b, c0 + j);
#pragma unroll
        for (int i = 0; i < 4; ++i) {
            float4 o;
            o.x = qv[0] * accd[i][0];
            o.y = qv[1] * accd[i][1];
            o.z = qv[2] * accd[i][2];
            o.w = qv[3] * accd[i][3];
            *reinterpret_cast<float4*>(&Es[(e0 + i) * 64 + (c0 ^ 16)]) = o;
        }
    }
    __syncthreads();   // CPs/Ks readers done -> Ss may overwrite

    // Ss chunk
    for (int idx = t; idx < 4096; idx += 256) {
        const int hl_ = idx >> 6, e = idx & 63;
        Ss[hl_ * 66 + e] = Sval(l, r, ll, rl, hc * 64 + hl_, e);
    }
    __syncthreads();

    // SE rows: SEs[h][m] = sum_e Ss[h][e]*Es[e][m]
    {
        const int h = t >> 2;
        const int mg = (t & 3) * 16;
        float acc[16];
#pragma unroll
        for (int q = 0; q < 16; ++q) acc[q] = 0.f;
#pragma unroll 4
        for (int e = 0; e < 64; ++e) {
            const float s = Ss[h * 66 + e];
            const float* Er = Es + e * 64 + mg;
#pragma unroll
            for (int q = 0; q < 16; ++q) acc[q] += s * Er[q];
        }
#pragma unroll
        for (int q = 0; q < 16; ++q) SEs[h * 65 + mg + q] = acc[q];
    }
    __syncthreads();

    unsigned short* outp = SEf + (size_t)b * 65536 + hc * 8192;
#pragma unroll
    for (int it = 0; it < 4; ++it) {
        const int widx0 = it * 2048 + t * 8;
        const int fl = widx0 >> 10;
        const int hl = (widx0 >> 9) & 1;
        const int lx = (widx0 >> 3) & 63;
        const int m = (fl & 3) * 16 + (lx & 15);
        const int hb = (fl >> 2) * 32 + ((lx >> 4) & 3) * 8;
        unsigned short wv[8];
#pragma unroll
        for (int i = 0; i < 8; ++i) {
            short hh, ss;
            bf16_split(SEs[(hb + i) * 65 + m], hh, ss);
            wv[i] = hl ? (unsigned short)ss : (unsigned short)hh;
        }
        uint4 pk;
        pk.x = (unsigned)wv[0] | ((unsigned)wv[1] << 16);
        pk.y = (unsigned)wv[2] | ((unsigned)wv[3] << 16);
        pk.z = (unsigned)wv[4] | ((unsigned)wv[5] << 16);
        pk.w = (unsigned)wv[6] | ((unsigned)wv[7] << 16);
        *reinterpret_cast<uint4*>(outp + widx0) = pk;
    }
}

// out = x + ((x * SE_b) * S^T) via split-bf16 MFMA, LDS-staged x (hi/lo).
// 16-row tiles, n-split waves, XPAD=524. Byte-identical to R18. grid (256, 8).
__global__ __launch_bounds__(256, 4) void k_mix(const float* x,
                                                const unsigned short* SEf,
                                                const unsigned short* Sf,
                                                float* out) {
    __shared__ unsigned short xh[16 * XPAD];
    __shared__ unsigned short xl[16 * XPAD];
    __shared__ float Zs[16 * 68];
    const int b = blockIdx.y;
    const int r0 = blockIdx.x * 16;
    const int t = threadIdx.x;
    const int w = t >> 6;
    const int l = t & 63;
    const int lm = l & 15;
    const int lk = (l >> 4) * 8;
    const float* xb = x + (size_t)b * N_ * F_;
    float* outb = out + (size_t)b * N_ * F_;
    const unsigned short* sef = SEf + (size_t)b * 65536;

#pragma unroll 4
    for (int it = 0; it < 8; ++it) {
        const int idx = it * 256 + t;
        const int row = idx >> 7, c4 = (idx & 127) * 4;
        const float4 v = *reinterpret_cast<const float4*>(
            xb + (size_t)(r0 + row) * F_ + c4);
        ushort4 hs, ls;
        short hh, ss;
        bf16_split(v.x, hh, ss); hs.x = (unsigned short)hh; ls.x = (unsigned short)ss;
        bf16_split(v.y, hh, ss); hs.y = (unsigned short)hh; ls.y = (unsigned short)ss;
        bf16_split(v.z, hh, ss); hs.z = (unsigned short)hh; ls.z = (unsigned short)ss;
        bf16_split(v.w, hh, ss); hs.w = (unsigned short)hh; ls.w = (unsigned short)ss;
        *reinterpret_cast<ushort4*>(&xh[row * XPAD + c4]) = hs;
        *reinterpret_cast<ushort4*>(&xl[row * XPAD + c4]) = ls;
    }
    __syncthreads();

    f32x4 ahh = {0.f, 0.f, 0.f, 0.f}, alh = ahh, ahl = ahh;
    const unsigned short* xhr = xh + lm * XPAD;
    const unsigned short* xlr = xl + lm * XPAD;
#pragma unroll 4
    for (int kk = 0; kk < 16; ++kk) {
        const int k0 = kk * 32 + lk;
        const bf16x8 ah = *reinterpret_cast<const bf16x8*>(xhr + k0);
        const bf16x8 al = *reinterpret_cast<const bf16x8*>(xlr + k0);
        const int o0 = (kk * 4 + w) * 1024 + l * 8;
        const bf16x8 bh = *reinterpret_cast<const bf16x8*>(sef + o0);
        const bf16x8 bl = *reinterpret_cast<const bf16x8*>(sef + o0 + 512);
        ahh = __builtin_amdgcn_mfma_f32_16x16x32_bf16(ah, bh, ahh, 0, 0, 0);
        alh = __builtin_amdgcn_mfma_f32_16x16x32_bf16(al, bh, alh, 0, 0, 0);
        ahl = __builtin_amdgcn_mfma_f32_16x16x32_bf16(ah, bl, ahl, 0, 0, 0);
    }
#pragma unroll
    for (int r = 0; r < 4; ++r) {
        const int zr = ((l >> 4) * 4 + r) * 68 + w * 16;
        Zs[zr + lm] = ahh[r] + alh[r] + ahl[r];
    }
    __syncthreads();

    bf16x8 zh0, zl0, zh1, zl1;
    {
        const float* zrow = &Zs[lm * 68];
#pragma unroll
        for (int i = 0; i < 8; ++i) {
            short hh, ss;
            bf16_split(zrow[lk + i], hh, ss);
            zh0[i] = hh; zl0[i] = ss;
            bf16_split(zrow[32 + lk + i], hh, ss);
            zh1[i] = hh; zl1[i] = ss;
        }
    }
    const int lrow0 = (l >> 4) * 4;
    const int orow0 = r0 + lrow0;
#pragma unroll 2
    for (int j2 = 0; j2 < 8; ++j2) {
        const int ht = w * 8 + j2;
        const int h0 = ht * 16 + lm;
        f32x4 ca = {0.f, 0.f, 0.f, 0.f};
        f32x4 cb;
#pragma unroll
        for (int r = 0; r < 4; ++r) {
            const int la = (lrow0 + r) * XPAD + h0;
            cb[r] = b2f(xh[la]) + b2f(xl[la]);
        }
        const int fb = ht * 2048 + l * 8;
        const bf16x8 bh0 = *reinterpret_cast<const bf16x8*>(Sf + fb);
        const bf16x8 bl0 = *reinterpret_cast<const bf16x8*>(Sf + fb + 512);
        const bf16x8 bh1 = *reinterpret_cast<const bf16x8*>(Sf + fb + 1024);
        const bf16x8 bl1 = *reinterpret_cast<const bf16x8*>(Sf + fb + 1536);
        ca = __builtin_amdgcn_mfma_f32_16x16x32_bf16(zh0, bh0, ca, 0, 0, 0);
        ca = __builtin_amdgcn_mfma_f32_16x16x32_bf16(zl0, bh0, ca, 0, 0, 0);
        ca = __builtin_amdgcn_mfma_f32_16x16x32_bf16(zh0, bl0, ca, 0, 0, 0);
        cb = __builtin_amdgcn_mfma_f32_16x16x32_bf16(zh1, bh1, cb, 0, 0, 0);
        cb = __builtin_amdgcn_mfma_f32_16x16x32_bf16(zl1, bh1, cb, 0, 0, 0);
        cb = __builtin_amdgcn_mfma_f32_16x16x32_bf16(zh1, bl1, cb, 0, 0, 0);
#pragma unroll
        for (int r = 0; r < 4; ++r)
            outb[(size_t)(orow0 + r) * F_ + h0] = ca[r] + cb[r];
    }
}

extern "C" void kernel_launch(void* const* d_in, const int* in_sizes, int n_in,
                              void* d_out, int out_size, void* d_ws, size_t ws_size,
                              hipStream_t stream) {
    (void)in_sizes; (void)n_in; (void)out_size; (void)ws_size;
    const float* x       = (const float*)d_in[0];
    const float* coeff   = (const float*)d_in[1];
    const float* gate    = (const float*)d_in[2];
    const float* coeff_l = (const float*)d_in[3];
    const float* gate_l  = (const float*)d_in[4];
    const float* comm    = (const float*)d_in[5];
    const float* l       = (const float*)d_in[6];
    const float* r       = (const float*)d_in[7];
    const float* ll      = (const float*)d_in[8];
    const float* rl      = (const float*)d_in[9];

    char* wsb = (char*)d_ws;
    float* GS   = (float*)(wsb);                              // 4096 f       @0
    unsigned short* SEf = (unsigned short*)(wsb + 147456);    // 8*65536 u16  @144K (1MB)
    unsigned short* Sf  = (unsigned short*)(wsb + 1196032);   // 65536 u16    @1168K (128K)
    float* Mws  = (float*)(wsb + 1327104);                    // 8*4096 f     @1296K
    float* CPws = (float*)(wsb + 1458176);                    // 8*4096 f     @1424K
    float* Kws  = (float*)(wsb + 1589248);                    // 8*4096 f     @1552K (ends 1680K)
    float* out = (float*)d_out;

    k_prep<<<dim3(64), dim3(256), 0, stream>>>(l, r, ll, rl, GS, Sf);
    k_pre<<<dim3(8), dim3(256), 0, stream>>>(coeff, gate, coeff_l, gate_l, comm, GS,
                                             Mws, CPws);
    k_inv<<<dim3(8), dim3(64), 0, stream>>>(Mws, Kws);
    k_sepost<<<dim3(8, 8), dim3(256), 0, stream>>>(coeff, coeff_l, l, r, ll, rl,
                                                   CPws, Kws, SEf);
    k_mix<<<dim3(256, 8), dim3(256), 0, stream>>>(x, SEf, Sf, out);
}

// Round 21
// 99.151 us; speedup vs baseline: 1.3127x; 1.0819x over previous
//
#include <hip/hip_runtime.h>

#define B_ 8
#define N_ 4096
#define F_ 512

typedef __attribute__((ext_vector_type(8))) short bf16x8;
typedef __attribute__((ext_vector_type(4))) float f32x4;

#define XPAD 524   // u16 row stride: 262 dw == 6 mod 32 -> distinct lane banks; 8B-aligned

// S (512 x 64) = [left | right | left_local | right_local], each [512][16] row-major.
__device__ __forceinline__ float Sval(const float* l, const float* r,
                                      const float* ll, const float* rl,
                                      int h, int e) {
    const int m = e >> 4, c = e & 15;
    const float* p = (m == 0) ? l : (m == 1) ? r : (m == 2) ? ll : rl;
    return p[h * 16 + c];
}

__device__ __forceinline__ float qval(const float* coeff, const float* coeff_l,
                                      int b, int j) {
    if (j < 16) return 1.f;
    if (j < 32) return coeff[b * 16 + (j - 16)];
    if (j < 48) return 1.f;
    return coeff_l[b * 16 + (j - 48)];
}

__device__ __forceinline__ float lane_bcast(float v, int lane) {
    return __int_as_float(__builtin_amdgcn_readlane(__float_as_int(v), lane));
}

__device__ __forceinline__ unsigned short bf16_rn(float x) {
    unsigned u = __float_as_uint(x);
    unsigned r = u + 0x7FFFu + ((u >> 16) & 1u);
    return (unsigned short)(r >> 16);
}

// split x ~= hi + lo, both bf16 (error ~2^-17 |x|)
__device__ __forceinline__ void bf16_split(float x, short& hi, short& lo) {
    const unsigned short h = bf16_rn(x);
    const float hf = __uint_as_float(((unsigned)h) << 16);
    const unsigned short s = bf16_rn(x - hf);
    hi = (short)h; lo = (short)s;
}

__device__ __forceinline__ float b2f(unsigned short u) {
    return __uint_as_float(((unsigned)u) << 16);
}

// ---- k_prep: GS row i + S-fragment f2=i for phase-2 B-operand. grid 64.
__global__ __launch_bounds__(256) void k_prep(const float* l, const float* r,
                                              const float* ll, const float* rl,
                                              float* GS, unsigned short* Sf) {
    __shared__ float red[4][64];
    const int i = blockIdx.x;
    const int t = threadIdx.x;
    const int j = t & 63, seg = t >> 6;

    {
        const int ht = i >> 1, eh = i & 1;
        for (int idx = t; idx < 512; idx += 256) {
            const int lx = idx >> 3, ii = idx & 7;
            const int h = ht * 16 + (lx & 15);
            const int e = eh * 32 + ((lx >> 4) & 3) * 8 + ii;
            short hh, ss;
            bf16_split(Sval(l, r, ll, rl, h, e), hh, ss);
            Sf[(i * 2 + 0) * 512 + idx] = (unsigned short)hh;
            Sf[(i * 2 + 1) * 512 + idx] = (unsigned short)ss;
        }
    }

    float acc = 0.f;
    const int h0 = seg * 128;
    for (int h = h0; h < h0 + 128; ++h)
        acc += Sval(l, r, ll, rl, h, i) * Sval(l, r, ll, rl, h, j);
    red[seg][j] = acc;
    __syncthreads();
    if (t < 64) GS[i * 64 + t] = red[0][t] + red[1][t] + red[2][t] + red[3][t];
}

// ---- k_pre: build CP and M = I - 0.5 CQ^T GS CP -> Mws, CPws. 8 blocks.
__global__ __launch_bounds__(256) void k_pre(const float* coeff, const float* gate,
                                             const float* coeff_l, const float* gate_l,
                                             const float* comm, const float* GS,
                                             float* Mws, float* CPws) {
    __shared__ float GST[4096];
    __shared__ float CPs[4096];
    __shared__ float ABs[2048];
    __shared__ float u1s[32], u2s[32];

    const int b = blockIdx.x, t = threadIdx.x;
    const int tx = t & 15, ty = t >> 4;
    const float g = gate[b], gl = gate_l[b];
    const float cs = comm[b] / 12.0f;

    if (t < 32) {
        u1s[t] = (t < 16) ? g * coeff[b * 16 + t] : -g;
        u2s[t] = (t < 16) ? gl * coeff_l[b * 16 + t] : -gl;
    }
    for (int idx = t; idx < 4096; idx += 256) {
        const int i = idx & 63, e = idx >> 6;
        GST[idx] = -0.5f * qval(coeff, coeff_l, b, i) * GS[(i ^ 16) * 64 + e];
    }
    __syncthreads();

    for (int idx = t; idx < 2048; idx += 256) {
        const int which = idx >> 10;
        const int i = (idx >> 5) & 31, j = idx & 31;
        float val;
        if (which == 0) {
            const int v2i = (i < 16) ? 48 + i : 16 + i;
            const float v2sc = (i < 16) ? 1.f : coeff_l[b * 16 + (i - 16)];
            val = v2sc * u1s[j] * GS[v2i * 64 + j];
        } else {
            const int v1i = (i < 16) ? 16 + i : i - 16;
            const float v1sc = (i < 16) ? 1.f : coeff[b * 16 + (i - 16)];
            val = v1sc * u2s[j] * GS[v1i * 64 + 32 + j];
        }
        ABs[idx] = val;
    }
    __syncthreads();

    for (int idx = t; idx < 4096; idx += 256) {
        const int e = idx >> 6, j = idx & 63;
        float val = 0.f;
        if (j < 32) {
            if (e == j) val += 0.5f * u1s[j];
            if (e >= 32) val += cs * u2s[e - 32] * ABs[(e - 32) * 32 + j];
        } else {
            const int jp = j - 32;
            if (e == 32 + jp) val += 0.5f * u2s[jp];
            if (e < 32) val -= cs * u1s[e] * ABs[1024 + e * 32 + jp];
        }
        CPs[idx] = val;
        CPws[b * 4096 + idx] = val;
    }
    __syncthreads();

    {
        const int i0 = ty * 4, m0 = tx * 4;
        float acc[4][4];
#pragma unroll
        for (int i = 0; i < 4; ++i)
#pragma unroll
            for (int j = 0; j < 4; ++j) acc[i][j] = 0.f;
        for (int e = 0; e < 64; ++e) {
            const float4 av = *reinterpret_cast<const float4*>(&GST[e * 64 + i0]);
            const float4 bv = *reinterpret_cast<const float4*>(&CPs[e * 64 + m0]);
            const float a[4] = {av.x, av.y, av.z, av.w};
            const float bb[4] = {bv.x, bv.y, bv.z, bv.w};
#pragma unroll
            for (int i = 0; i < 4; ++i)
#pragma unroll
                for (int j = 0; j < 4; ++j) acc[i][j] += a[i] * bb[j];
        }
#pragma unroll
        for (int i = 0; i < 4; ++i) {
            float4 o;
            o.x = acc[i][0] + (((i0 + i) == (m0 + 0)) ? 1.f : 0.f);
            o.y = acc[i][1] + (((i0 + i) == (m0 + 1)) ? 1.f : 0.f);
            o.z = acc[i][2] + (((i0 + i) == (m0 + 2)) ? 1.f : 0.f);
            o.w = acc[i][3] + (((i0 + i) == (m0 + 3)) ? 1.f : 0.f);
            *reinterpret_cast<float4*>(&Mws[b * 4096 + (i0 + i) * 64 + m0]) = o;
        }
    }
}

// ---- k_inv: 4-WAVE blocked Gauss-Jordan, ALL-LITERAL indices (rule #20).
// Wave wv owns rows 16wv..16wv+15 (a[16] in VGPRs). 8 column-panels; owning
// wave runs 8 in-panel steps (akp capture points identical to the R12-verified
// blocked GJ; algebra hardware-verified correct in R16's fused kernel) and
// publishes akp[8][64] via LDS; 2 barriers/panel; trailing rows parallelized
// across 4 waves (4x less serial depth than the single-wave version).
// R10's 4-wave attempt spilled (runtime a[] idx -> VGPR 24); this is the
// literal-index version, standalone, launch_bounds(256,1).
#define DO16(M) M(0) M(1) M(2) M(3) M(4) M(5) M(6) M(7) \
                M(8) M(9) M(10) M(11) M(12) M(13) M(14) M(15)

#define GJL(I) a[I] = Mws[base + (wv * 16 + (I)) * 64 + ln];
#define GJS(I) Kws[base + (wv * 16 + (I)) * 64 + ln] = a[I];

#define IP_UPD(I, BQ, J) \
    if ((I) != (J)) { \
        const float f_ = lane_bcast(a[(BQ) + (I)], g8 + (J)); \
        a[(BQ) + (I)] = __builtin_fmaf(-f_, akp##J, a[(BQ) + (I)]); \
    }

#define IP_STEP(BQ, J) { \
    const float dk = lane_bcast(a[(BQ) + (J)], g8 + (J)); \
    const float pinv = 1.0f / dk; \
    a[(BQ) + (J)] = (ln == g8 + (J)) ? pinv : a[(BQ) + (J)] * pinv; \
    akp##J = a[(BQ) + (J)] + ((ln == g8 + (J)) ? 1.0f : 0.0f); \
    akp_lds[(J) * 64 + ln] = akp##J; \
    IP_UPD(0, BQ, J) IP_UPD(1, BQ, J) IP_UPD(2, BQ, J) IP_UPD(3, BQ, J) \
    IP_UPD(4, BQ, J) IP_UPD(5, BQ, J) IP_UPD(6, BQ, J) IP_UPD(7, BQ, J) }

#define IP_ALL(BQ) \
    IP_STEP(BQ, 0) IP_STEP(BQ, 1) IP_STEP(BQ, 2) IP_STEP(BQ, 3) \
    IP_STEP(BQ, 4) IP_STEP(BQ, 5) IP_STEP(BQ, 6) IP_STEP(BQ, 7)

#define TRAIL(I) \
    if (((wv * 16 + (I)) >> 3) != G) { \
        const float f0 = lane_bcast(a[I], g8 + 0); \
        const float f1 = lane_bcast(a[I], g8 + 1); \
        const float f2 = lane_bcast(a[I], g8 + 2); \
        const float f3 = lane_bcast(a[I], g8 + 3); \
        const float f4 = lane_bcast(a[I], g8 + 4); \
        const float f5 = lane_bcast(a[I], g8 + 5); \
        const float f6 = lane_bcast(a[I], g8 + 6); \
        const float f7 = lane_bcast(a[I], g8 + 7); \
        a[I] = __builtin_fmaf(-f0, akp0, a[I]); \
        a[I] = __builtin_fmaf(-f1, akp1, a[I]); \
        a[I] = __builtin_fmaf(-f2, akp2, a[I]); \
        a[I] = __builtin_fmaf(-f3, akp3, a[I]); \
        a[I] = __builtin_fmaf(-f4, akp4, a[I]); \
        a[I] = __builtin_fmaf(-f5, akp5, a[I]); \
        a[I] = __builtin_fmaf(-f6, akp6, a[I]); \
        a[I] = __builtin_fmaf(-f7, akp7, a[I]); \
    }

__global__ __launch_bounds__(256, 1) void k_inv(const float* Mws, float* Kws) {
    __shared__ float akp_lds[512];
    const int b = blockIdx.x, t = threadIdx.x;
    const int wv = t >> 6, ln = t & 63;
    const int base = b * 4096;
    float a[16];
    DO16(GJL)
    float akp0, akp1, akp2, akp3, akp4, akp5, akp6, akp7;
    for (int G = 0; G < 8; ++G) {
        const int g8 = G * 8;
        __syncthreads();   // prev-panel akp readers done / buffer free
        if (wv == (G >> 1)) {
            if ((G & 1) == 0) { IP_ALL(0) } else { IP_ALL(8) }
        }
        __syncthreads();
        if (wv != (G >> 1)) {
            akp0 = akp_lds[0 * 64 + ln];
            akp1 = akp_lds[1 * 64 + ln];
            akp2 = akp_lds[2 * 64 + ln];
            akp3 = akp_lds[3 * 64 + ln];
            akp4 = akp_lds[4 * 64 + ln];
            akp5 = akp_lds[5 * 64 + ln];
            akp6 = akp_lds[6 * 64 + ln];
            akp7 = akp_lds[7 * 64 + ln];
        }
        DO16(TRAIL)
    }
    DO16(GJS)
}

// ---- k_sepost: E = q ⊙ (CP*K) (Newton dropped — R19-verified, absmax 0.031
// vs 0.11 threshold) + SE-chunk + fragment emission. grid (hc=8, b=8).
__global__ __launch_bounds__(256) void k_sepost(const float* coeff, const float* coeff_l,
                                                const float* l, const float* r,
                                                const float* ll, const float* rl,
                                                const float* CPws, const float* Kws,
                                                unsigned short* SEf) {
    __shared__ float smem[12480];
    float* CPs = smem;          // [0,4096)
    float* Ks  = smem + 4224;   // [4224,8320)
    float* Es  = smem + 8384;   // [8384,12480)  live to end
    float* Ss  = smem;          // phase B [0,4224)
    float* SEs = smem + 4224;   // phase B [4224,8384)

    const int b = blockIdx.y, hc = blockIdx.x, t = threadIdx.x;
    const int tx = t & 15, ty = t >> 4;

    for (int idx = t; idx < 4096; idx += 256) {
        CPs[idx] = CPws[b * 4096 + idx];
        Ks[idx] = Kws[b * 4096 + idx];
    }
    __syncthreads();

    // Td = CP*K in regs -> E[e][(c)^16] = q(c)*Td[e][c] straight to Es
    {
        const int e0 = ty * 4, c0 = tx * 4;
        float accd[4][4];
#pragma unroll
        for (int i = 0; i < 4; ++i)
#pragma unroll
            for (int j = 0; j < 4; ++j) accd[i][j] = 0.f;
        for (int q = 0; q < 64; ++q) {
            const float4 bv = *reinterpret_cast<const float4*>(&Ks[q * 64 + c0]);
            const float bb[4] = {bv.x, bv.y, bv.z, bv.w};
            float ad[4];
#pragma unroll
            for (int i = 0; i < 4; ++i) ad[i] = CPs[(e0 + i) * 64 + q];
#pragma unroll
            for (int i = 0; i < 4; ++i)
#pragma unroll
                for (int j = 0; j < 4; ++j) accd[i][j] += ad[i] * bb[j];
        }
        float qv[4];
#pragma unroll
        for (int j = 0; j < 4; ++j) qv[j] = qval(coeff, coeff_l, b, c0 + j);
#pragma unroll
        for (int i = 0; i < 4; ++i) {
            float4 o;
            o.x = qv[0] * accd[i][0];
            o.y = qv[1] * accd[i][1];
            o.z = qv[2] * accd[i][2];
            o.w = qv[3] * accd[i][3];
            *reinterpret_cast<float4*>(&Es[(e0 + i) * 64 + (c0 ^ 16)]) = o;
        }
    }
    __syncthreads();   // CPs/Ks readers done -> Ss may overwrite

    // Ss chunk
    for (int idx = t; idx < 4096; idx += 256) {
        const int hl_ = idx >> 6, e = idx & 63;
        Ss[hl_ * 66 + e] = Sval(l, r, ll, rl, hc * 64 + hl_, e);
    }
    __syncthreads();

    // SE rows: SEs[h][m] = sum_e Ss[h][e]*Es[e][m]
    {
        const int h = t >> 2;
        const int mg = (t & 3) * 16;
        float acc[16];
#pragma unroll
        for (int q = 0; q < 16; ++q) acc[q] = 0.f;
#pragma unroll 4
        for (int e = 0; e < 64; ++e) {
            const float s = Ss[h * 66 + e];
            const float* Er = Es + e * 64 + mg;
#pragma unroll
            for (int q = 0; q < 16; ++q) acc[q] += s * Er[q];
        }
#pragma unroll
        for (int q = 0; q < 16; ++q) SEs[h * 65 + mg + q] = acc[q];
    }
    __syncthreads();

    unsigned short* outp = SEf + (size_t)b * 65536 + hc * 8192;
#pragma unroll
    for (int it = 0; it < 4; ++it) {
        const int widx0 = it * 2048 + t * 8;
        const int fl = widx0 >> 10;
        const int hl = (widx0 >> 9) & 1;
        const int lx = (widx0 >> 3) & 63;
        const int m = (fl & 3) * 16 + (lx & 15);
        const int hb = (fl >> 2) * 32 + ((lx >> 4) & 3) * 8;
        unsigned short wv[8];
#pragma unroll
        for (int i = 0; i < 8; ++i) {
            short hh, ss;
            bf16_split(SEs[(hb + i) * 65 + m], hh, ss);
            wv[i] = hl ? (unsigned short)ss : (unsigned short)hh;
        }
        uint4 pk;
        pk.x = (unsigned)wv[0] | ((unsigned)wv[1] << 16);
        pk.y = (unsigned)wv[2] | ((unsigned)wv[3] << 16);
        pk.z = (unsigned)wv[4] | ((unsigned)wv[5] << 16);
        pk.w = (unsigned)wv[6] | ((unsigned)wv[7] << 16);
        *reinterpret_cast<uint4*>(outp + widx0) = pk;
    }
}

// out = x + ((x * SE_b) * S^T) via split-bf16 MFMA, LDS-staged x (hi/lo).
// 16-row tiles, n-split waves, XPAD=524. Byte-identical to R18/R19. grid (256, 8).
__global__ __launch_bounds__(256, 4) void k_mix(const float* x,
                                                const unsigned short* SEf,
                                                const unsigned short* Sf,
                                                float* out) {
    __shared__ unsigned short xh[16 * XPAD];
    __shared__ unsigned short xl[16 * XPAD];
    __shared__ float Zs[16 * 68];
    const int b = blockIdx.y;
    const int r0 = blockIdx.x * 16;
    const int t = threadIdx.x;
    const int w = t >> 6;
    const int l = t & 63;
    const int lm = l & 15;
    const int lk = (l >> 4) * 8;
    const float* xb = x + (size_t)b * N_ * F_;
    float* outb = out + (size_t)b * N_ * F_;
    const unsigned short* sef = SEf + (size_t)b * 65536;

#pragma unroll 4
    for (int it = 0; it < 8; ++it) {
        const int idx = it * 256 + t;
        const int row = idx >> 7, c4 = (idx & 127) * 4;
        const float4 v = *reinterpret_cast<const float4*>(
            xb + (size_t)(r0 + row) * F_ + c4);
        ushort4 hs, ls;
        short hh, ss;
        bf16_split(v.x, hh, ss); hs.x = (unsigned short)hh; ls.x = (unsigned short)ss;
        bf16_split(v.y, hh, ss); hs.y = (unsigned short)hh; ls.y = (unsigned short)ss;
        bf16_split(v.z, hh, ss); hs.z = (unsigned short)hh; ls.z = (unsigned short)ss;
        bf16_split(v.w, hh, ss); hs.w = (unsigned short)hh; ls.w = (unsigned short)ss;
        *reinterpret_cast<ushort4*>(&xh[row * XPAD + c4]) = hs;
        *reinterpret_cast<ushort4*>(&xl[row * XPAD + c4]) = ls;
    }
    __syncthreads();

    f32x4 ahh = {0.f, 0.f, 0.f, 0.f}, alh = ahh, ahl = ahh;
    const unsigned short* xhr = xh + lm * XPAD;
    const unsigned short* xlr = xl + lm * XPAD;
#pragma unroll 4
    for (int kk = 0; kk < 16; ++kk) {
        const int k0 = kk * 32 + lk;
        const bf16x8 ah = *reinterpret_cast<const bf16x8*>(xhr + k0);
        const bf16x8 al = *reinterpret_cast<const bf16x8*>(xlr + k0);
        const int o0 = (kk * 4 + w) * 1024 + l * 8;
        const bf16x8 bh = *reinterpret_cast<const bf16x8*>(sef + o0);
        const bf16x8 bl = *reinterpret_cast<const bf16x8*>(sef + o0 + 512);
        ahh = __builtin_amdgcn_mfma_f32_16x16x32_bf16(ah, bh, ahh, 0, 0, 0);
        alh = __builtin_amdgcn_mfma_f32_16x16x32_bf16(al, bh, alh, 0, 0, 0);
        ahl = __builtin_amdgcn_mfma_f32_16x16x32_bf16(ah, bl, ahl, 0, 0, 0);
    }
#pragma unroll
    for (int r = 0; r < 4; ++r) {
        const int zr = ((l >> 4) * 4 + r) * 68 + w * 16;
        Zs[zr + lm] = ahh[r] + alh[r] + ahl[r];
    }
    __syncthreads();

    bf16x8 zh0, zl0, zh1, zl1;
    {
        const float* zrow = &Zs[lm * 68];
#pragma unroll
        for (int i = 0; i < 8; ++i) {
            short hh, ss;
            bf16_split(zrow[lk + i], hh, ss);
            zh0[i] = hh; zl0[i] = ss;
            bf16_split(zrow[32 + lk + i], hh, ss);
            zh1[i] = hh; zl1[i] = ss;
        }
    }
    const int lrow0 = (l >> 4) * 4;
    const int orow0 = r0 + lrow0;
#pragma unroll 2
    for (int j2 = 0; j2 < 8; ++j2) {
        const int ht = w * 8 + j2;
        const int h0 = ht * 16 + lm;
        f32x4 ca = {0.f, 0.f, 0.f, 0.f};
        f32x4 cb;
#pragma unroll
        for (int r = 0; r < 4; ++r) {
            const int la = (lrow0 + r) * XPAD + h0;
            cb[r] = b2f(xh[la]) + b2f(xl[la]);
        }
        const int fb = ht * 2048 + l * 8;
        const bf16x8 bh0 = *reinterpret_cast<const bf16x8*>(Sf + fb);
        const bf16x8 bl0 = *reinterpret_cast<const bf16x8*>(Sf + fb + 512);
        const bf16x8 bh1 = *reinterpret_cast<const bf16x8*>(Sf + fb + 1024);
        const bf16x8 bl1 = *reinterpret_cast<const bf16x8*>(Sf + fb + 1536);
        ca = __builtin_amdgcn_mfma_f32_16x16x32_bf16(zh0, bh0, ca, 0, 0, 0);
        ca = __builtin_amdgcn_mfma_f32_16x16x32_bf16(zl0, bh0, ca, 0, 0, 0);
        ca = __builtin_amdgcn_mfma_f32_16x16x32_bf16(zh0, bl0, ca, 0, 0, 0);
        cb = __builtin_amdgcn_mfma_f32_16x16x32_bf16(zh1, bh1, cb, 0, 0, 0);
        cb = __builtin_amdgcn_mfma_f32_16x16x32_bf16(zl1, bh1, cb, 0, 0, 0);
        cb = __builtin_amdgcn_mfma_f32_16x16x32_bf16(zh1, bl1, cb, 0, 0, 0);
#pragma unroll
        for (int r = 0; r < 4; ++r)
            outb[(size_t)(orow0 + r) * F_ + h0] = ca[r] + cb[r];
    }
}

extern "C" void kernel_launch(void* const* d_in, const int* in_sizes, int n_in,
                              void* d_out, int out_size, void* d_ws, size_t ws_size,
                              hipStream_t stream) {
    (void)in_sizes; (void)n_in; (void)out_size; (void)ws_size;
    const float* x       = (const float*)d_in[0];
    const float* coeff   = (const float*)d_in[1];
    const float* gate    = (const float*)d_in[2];
    const float* coeff_l = (const float*)d_in[3];
    const float* gate_l  = (const float*)d_in[4];
    const float* comm    = (const float*)d_in[5];
    const float* l       = (const float*)d_in[6];
    const float* r       = (const float*)d_in[7];
    const float* ll      = (const float*)d_in[8];
    const float* rl      = (const float*)d_in[9];

    char* wsb = (char*)d_ws;
    float* GS   = (float*)(wsb);                              // 4096 f       @0
    unsigned short* SEf = (unsigned short*)(wsb + 147456);    // 8*65536 u16  @144K (1MB)
    unsigned short* Sf  = (unsigned short*)(wsb + 1196032);   // 65536 u16    @1168K (128K)
    float* Mws  = (float*)(wsb + 1327104);                    // 8*4096 f     @1296K
    float* CPws = (float*)(wsb + 1458176);                    // 8*4096 f     @1424K
    float* Kws  = (float*)(wsb + 1589248);                    // 8*4096 f     @1552K (ends 1680K)
    float* out = (float*)d_out;

    k_prep<<<dim3(64), dim3(256), 0, stream>>>(l, r, ll, rl, GS, Sf);
    k_pre<<<dim3(8), dim3(256), 0, stream>>>(coeff, gate, coeff_l, gate_l, comm, GS,
                                             Mws, CPws);
    k_inv<<<dim3(8), dim3(256), 0, stream>>>(Mws, Kws);
    k_sepost<<<dim3(8, 8), dim3(256), 0, stream>>>(coeff, coeff_l, l, r, ll, rl,
                                                   CPws, Kws, SEf);
    k_mix<<<dim3(256, 8), dim3(256), 0, stream>>>(x, SEf, Sf, out);
}

// Round 22
// 99.069 us; speedup vs baseline: 1.3138x; 1.0008x over previous
//
#include <hip/hip_runtime.h>

#define B_ 8
#define N_ 4096
#define F_ 512

typedef __attribute__((ext_vector_type(8))) short bf16x8;
typedef __attribute__((ext_vector_type(4))) float f32x4;

#define XPAD 524   // u16 row stride: 262 dw == 6 mod 32 -> distinct lane banks; 8B-aligned

// S (512 x 64) = [left | right | left_local | right_local], each [512][16] row-major.
__device__ __forceinline__ float Sval(const float* l, const float* r,
                                      const float* ll, const float* rl,
                                      int h, int e) {
    const int m = e >> 4, c = e & 15;
    const float* p = (m == 0) ? l : (m == 1) ? r : (m == 2) ? ll : rl;
    return p[h * 16 + c];
}

__device__ __forceinline__ float qval(const float* coeff, const float* coeff_l,
                                      int b, int j) {
    if (j < 16) return 1.f;
    if (j < 32) return coeff[b * 16 + (j - 16)];
    if (j < 48) return 1.f;
    return coeff_l[b * 16 + (j - 48)];
}

__device__ __forceinline__ float lane_bcast(float v, int lane) {
    return __int_as_float(__builtin_amdgcn_readlane(__float_as_int(v), lane));
}

__device__ __forceinline__ unsigned short bf16_rn(float x) {
    unsigned u = __float_as_uint(x);
    unsigned r = u + 0x7FFFu + ((u >> 16) & 1u);
    return (unsigned short)(r >> 16);
}

// split x ~= hi + lo, both bf16 (error ~2^-17 |x|)
__device__ __forceinline__ void bf16_split(float x, short& hi, short& lo) {
    const unsigned short h = bf16_rn(x);
    const float hf = __uint_as_float(((unsigned)h) << 16);
    const unsigned short s = bf16_rn(x - hf);
    hi = (short)h; lo = (short)s;
}

__device__ __forceinline__ float b2f(unsigned short u) {
    return __uint_as_float(((unsigned)u) << 16);
}

// ---- k_prep: GS row i + S-fragment f2=i for phase-2 B-operand. grid 64.
__global__ __launch_bounds__(256) void k_prep(const float* l, const float* r,
                                              const float* ll, const float* rl,
                                              float* GS, unsigned short* Sf) {
    __shared__ float red[4][64];
    const int i = blockIdx.x;
    const int t = threadIdx.x;
    const int j = t & 63, seg = t >> 6;

    {
        const int ht = i >> 1, eh = i & 1;
        for (int idx = t; idx < 512; idx += 256) {
            const int lx = idx >> 3, ii = idx & 7;
            const int h = ht * 16 + (lx & 15);
            const int e = eh * 32 + ((lx >> 4) & 3) * 8 + ii;
            short hh, ss;
            bf16_split(Sval(l, r, ll, rl, h, e), hh, ss);
            Sf[(i * 2 + 0) * 512 + idx] = (unsigned short)hh;
            Sf[(i * 2 + 1) * 512 + idx] = (unsigned short)ss;
        }
    }

    float acc = 0.f;
    const int h0 = seg * 128;
    for (int h = h0; h < h0 + 128; ++h)
        acc += Sval(l, r, ll, rl, h, i) * Sval(l, r, ll, rl, h, j);
    red[seg][j] = acc;
    __syncthreads();
    if (t < 64) GS[i * 64 + t] = red[0][t] + red[1][t] + red[2][t] + red[3][t];
}

// ---- GJ literal-index macros (rule #20). GJL reads Ms from LDS (ds_read);
// algebra + capture points identical to the R20-proven standalone 4-wave GJ.
#define DO16(M) M(0) M(1) M(2) M(3) M(4) M(5) M(6) M(7) \
                M(8) M(9) M(10) M(11) M(12) M(13) M(14) M(15)

#define GJL(I) a[I] = Ms[(wv * 16 + (I)) * 64 + ln];
#define GJS(I) Kws[base + (wv * 16 + (I)) * 64 + ln] = a[I];

#define IP_UPD(I, BQ, J) \
    if ((I) != (J)) { \
        const float f_ = lane_bcast(a[(BQ) + (I)], g8 + (J)); \
        a[(BQ) + (I)] = __builtin_fmaf(-f_, akp##J, a[(BQ) + (I)]); \
    }

#define IP_STEP(BQ, J) { \
    const float dk = lane_bcast(a[(BQ) + (J)], g8 + (J)); \
    const float pinv = 1.0f / dk; \
    a[(BQ) + (J)] = (ln == g8 + (J)) ? pinv : a[(BQ) + (J)] * pinv; \
    akp##J = a[(BQ) + (J)] + ((ln == g8 + (J)) ? 1.0f : 0.0f); \
    akp_lds[(J) * 64 + ln] = akp##J; \
    IP_UPD(0, BQ, J) IP_UPD(1, BQ, J) IP_UPD(2, BQ, J) IP_UPD(3, BQ, J) \
    IP_UPD(4, BQ, J) IP_UPD(5, BQ, J) IP_UPD(6, BQ, J) IP_UPD(7, BQ, J) }

#define IP_ALL(BQ) \
    IP_STEP(BQ, 0) IP_STEP(BQ, 1) IP_STEP(BQ, 2) IP_STEP(BQ, 3) \
    IP_STEP(BQ, 4) IP_STEP(BQ, 5) IP_STEP(BQ, 6) IP_STEP(BQ, 7)

#define TRAIL(I) \
    if (((wv * 16 + (I)) >> 3) != G) { \
        const float f0 = lane_bcast(a[I], g8 + 0); \
        const float f1 = lane_bcast(a[I], g8 + 1); \
        const float f2 = lane_bcast(a[I], g8 + 2); \
        const float f3 = lane_bcast(a[I], g8 + 3); \
        const float f4 = lane_bcast(a[I], g8 + 4); \
        const float f5 = lane_bcast(a[I], g8 + 5); \
        const float f6 = lane_bcast(a[I], g8 + 6); \
        const float f7 = lane_bcast(a[I], g8 + 7); \
        a[I] = __builtin_fmaf(-f0, akp0, a[I]); \
        a[I] = __builtin_fmaf(-f1, akp1, a[I]); \
        a[I] = __builtin_fmaf(-f2, akp2, a[I]); \
        a[I] = __builtin_fmaf(-f3, akp3, a[I]); \
        a[I] = __builtin_fmaf(-f4, akp4, a[I]); \
        a[I] = __builtin_fmaf(-f5, akp5, a[I]); \
        a[I] = __builtin_fmaf(-f6, akp6, a[I]); \
        a[I] = __builtin_fmaf(-f7, akp7, a[I]); \
    }

// ---- k_presolve: k_pre (build M/CP) + R20's 4-wave blocked GJ fused.
// grid 8, 256 thr, launch_bounds(256,1). Removes the k_inv launch gap and the
// Mws global round-trip (GJ sources M straight from LDS). No phases follow the
// GJ (unlike R15/R16's failed mega-fusion) -> no extra register pressure.
// LDS (floats): GST@0 | CPs@4096 | ABs/Ms@8192 | akp@12288 | u1/u2@12800.
__global__ __launch_bounds__(256, 1) void k_presolve(
        const float* coeff, const float* gate,
        const float* coeff_l, const float* gate_l,
        const float* comm, const float* GS,
        float* CPws, float* Kws) {
    __shared__ float smem[12864];
    float* GST = smem;
    float* CPs = smem + 4096;
    float* ABs = smem + 8192;
    float* Ms  = smem + 8192;
    float* akp_lds = smem + 12288;
    float* u1s = smem + 12800;
    float* u2s = smem + 12832;

    const int b = blockIdx.x, t = threadIdx.x;
    const int tx = t & 15, ty = t >> 4;
    const float g = gate[b], gl = gate_l[b];
    const float cs = comm[b] / 12.0f;

    // (1) u1/u2 + GST
    if (t < 32) {
        u1s[t] = (t < 16) ? g * coeff[b * 16 + t] : -g;
        u2s[t] = (t < 16) ? gl * coeff_l[b * 16 + t] : -gl;
    }
    for (int idx = t; idx < 4096; idx += 256) {
        const int i = idx & 63, e = idx >> 6;
        GST[idx] = -0.5f * qval(coeff, coeff_l, b, i) * GS[(i ^ 16) * 64 + e];
    }
    __syncthreads();

    // (2) ABs
    for (int idx = t; idx < 2048; idx += 256) {
        const int which = idx >> 10;
        const int i = (idx >> 5) & 31, j = idx & 31;
        float val;
        if (which == 0) {
            const int v2i = (i < 16) ? 48 + i : 16 + i;
            const float v2sc = (i < 16) ? 1.f : coeff_l[b * 16 + (i - 16)];
            val = v2sc * u1s[j] * GS[v2i * 64 + j];
        } else {
            const int v1i = (i < 16) ? 16 + i : i - 16;
            const float v1sc = (i < 16) ? 1.f : coeff[b * 16 + (i - 16)];
            val = v1sc * u2s[j] * GS[v1i * 64 + 32 + j];
        }
        ABs[idx] = val;
    }
    __syncthreads();

    // (3) CP -> LDS + CPws
    for (int idx = t; idx < 4096; idx += 256) {
        const int e = idx >> 6, j = idx & 63;
        float val = 0.f;
        if (j < 32) {
            if (e == j) val += 0.5f * u1s[j];
            if (e >= 32) val += cs * u2s[e - 32] * ABs[(e - 32) * 32 + j];
        } else {
            const int jp = j - 32;
            if (e == 32 + jp) val += 0.5f * u2s[jp];
            if (e < 32) val -= cs * u1s[e] * ABs[1024 + e * 32 + jp];
        }
        CPs[idx] = val;
        CPws[b * 4096 + idx] = val;
    }
    __syncthreads();

    // (4) M = I + GST^T*CP -> Ms (overwrites ABs after the barrier)
    {
        const int i0 = ty * 4, m0 = tx * 4;
        float acc[4][4];
#pragma unroll
        for (int i = 0; i < 4; ++i)
#pragma unroll
            for (int j = 0; j < 4; ++j) acc[i][j] = 0.f;
        for (int e = 0; e < 64; ++e) {
            const float4 av = *reinterpret_cast<const float4*>(&GST[e * 64 + i0]);
            const float4 bv = *reinterpret_cast<const float4*>(&CPs[e * 64 + m0]);
            const float a[4] = {av.x, av.y, av.z, av.w};
            const float bb[4] = {bv.x, bv.y, bv.z, bv.w};
#pragma unroll
            for (int i = 0; i < 4; ++i)
#pragma unroll
                for (int j = 0; j < 4; ++j) acc[i][j] += a[i] * bb[j];
        }
        __syncthreads();   // ABs readers done before Ms overwrite
#pragma unroll
        for (int i = 0; i < 4; ++i)
#pragma unroll
            for (int j = 0; j < 4; ++j)
                Ms[(i0 + i) * 64 + m0 + j] =
                    acc[i][j] + (((i0 + i) == (m0 + j)) ? 1.f : 0.f);
    }
    __syncthreads();

    // (5) 4-wave blocked GJ (R20-proven; GJL now ds_read from Ms)
    {
        const int wv = t >> 6, ln = t & 63;
        const int base = b * 4096;
        float a[16];
        DO16(GJL)
        float akp0, akp1, akp2, akp3, akp4, akp5, akp6, akp7;
        for (int G = 0; G < 8; ++G) {
            const int g8 = G * 8;
            __syncthreads();   // prev-panel akp readers done / buffer free
            if (wv == (G >> 1)) {
                if ((G & 1) == 0) { IP_ALL(0) } else { IP_ALL(8) }
            }
            __syncthreads();
            if (wv != (G >> 1)) {
                akp0 = akp_lds[0 * 64 + ln];
                akp1 = akp_lds[1 * 64 + ln];
                akp2 = akp_lds[2 * 64 + ln];
                akp3 = akp_lds[3 * 64 + ln];
                akp4 = akp_lds[4 * 64 + ln];
                akp5 = akp_lds[5 * 64 + ln];
                akp6 = akp_lds[6 * 64 + ln];
                akp7 = akp_lds[7 * 64 + ln];
            }
            DO16(TRAIL)
        }
        DO16(GJS)
    }
}

// ---- k_sepost: E = q ⊙ (CP*K) (Newton dropped — R19-verified, absmax 0.031
// vs 0.11 threshold) + SE-chunk + fragment emission. grid (hc=8, b=8).
__global__ __launch_bounds__(256) void k_sepost(const float* coeff, const float* coeff_l,
                                                const float* l, const float* r,
                                                const float* ll, const float* rl,
                                                const float* CPws, const float* Kws,
                                                unsigned short* SEf) {
    __shared__ float smem[12480];
    float* CPs = smem;          // [0,4096)
    float* Ks  = smem + 4224;   // [4224,8320)
    float* Es  = smem + 8384;   // [8384,12480)  live to end
    float* Ss  = smem;          // phase B [0,4224)
    float* SEs = smem + 4224;   // phase B [4224,8384)

    const int b = blockIdx.y, hc = blockIdx.x, t = threadIdx.x;
    const int tx = t & 15, ty = t >> 4;

    for (int idx = t; idx < 4096; idx += 256) {
        CPs[idx] = CPws[b * 4096 + idx];
        Ks[idx] = Kws[b * 4096 + idx];
    }
    __syncthreads();

    // Td = CP*K in regs -> E[e][(c)^16] = q(c)*Td[e][c] straight to Es
    {
        const int e0 = ty * 4, c0 = tx * 4;
        float accd[4][4];
#pragma unroll
        for (int i = 0; i < 4; ++i)
#pragma unroll
            for (int j = 0; j < 4; ++j) accd[i][j] = 0.f;
        for (int q = 0; q < 64; ++q) {
            const float4 bv = *reinterpret_cast<const float4*>(&Ks[q * 64 + c0]);
            const float bb[4] = {bv.x, bv.y, bv.z, bv.w};
            float ad[4];
#pragma unroll
            for (int i = 0; i < 4; ++i) ad[i] = CPs[(e0 + i) * 64 + q];
#pragma unroll
            for (int i = 0; i < 4; ++i)
#pragma unroll
                for (int j = 0; j < 4; ++j) accd[i][j] += ad[i] * bb[j];
        }
        float qv[4];
#pragma unroll
        for (int j = 0; j < 4; ++j) qv[j] = qval(coeff, coeff_l, b, c0 + j);
#pragma unroll
        for (int i = 0; i < 4; ++i) {
            float4 o;
            o.x = qv[0] * accd[i][0];
            o.y = qv[1] * accd[i][1];
            o.z = qv[2] * accd[i][2];
            o.w = qv[3] * accd[i][3];
            *reinterpret_cast<float4*>(&Es[(e0 + i) * 64 + (c0 ^ 16)]) = o;
        }
    }
    __syncthreads();   // CPs/Ks readers done -> Ss may overwrite

    // Ss chunk
    for (int idx = t; idx < 4096; idx += 256) {
        const int hl_ = idx >> 6, e = idx & 63;
        Ss[hl_ * 66 + e] = Sval(l, r, ll, rl, hc * 64 + hl_, e);
    }
    __syncthreads();

    // SE rows: SEs[h][m] = sum_e Ss[h][e]*Es[e][m]
    {
        const int h = t >> 2;
        const int mg = (t & 3) * 16;
        float acc[16];
#pragma unroll
        for (int q = 0; q < 16; ++q) acc[q] = 0.f;
#pragma unroll 4
        for (int e = 0; e < 64; ++e) {
            const float s = Ss[h * 66 + e];
            const float* Er = Es + e * 64 + mg;
#pragma unroll
            for (int q = 0; q < 16; ++q) acc[q] += s * Er[q];
        }
#pragma unroll
        for (int q = 0; q < 16; ++q) SEs[h * 65 + mg + q] = acc[q];
    }
    __syncthreads();

    unsigned short* outp = SEf + (size_t)b * 65536 + hc * 8192;
#pragma unroll
    for (int it = 0; it < 4; ++it) {
        const int widx0 = it * 2048 + t * 8;
        const int fl = widx0 >> 10;
        const int hl = (widx0 >> 9) & 1;
        const int lx = (widx0 >> 3) & 63;
        const int m = (fl & 3) * 16 + (lx & 15);
        const int hb = (fl >> 2) * 32 + ((lx >> 4) & 3) * 8;
        unsigned short wv[8];
#pragma unroll
        for (int i = 0; i < 8; ++i) {
            short hh, ss;
            bf16_split(SEs[(hb + i) * 65 + m], hh, ss);
            wv[i] = hl ? (unsigned short)ss : (unsigned short)hh;
        }
        uint4 pk;
        pk.x = (unsigned)wv[0] | ((unsigned)wv[1] << 16);
        pk.y = (unsigned)wv[2] | ((unsigned)wv[3] << 16);
        pk.z = (unsigned)wv[4] | ((unsigned)wv[5] << 16);
        pk.w = (unsigned)wv[6] | ((unsigned)wv[7] << 16);
        *reinterpret_cast<uint4*>(outp + widx0) = pk;
    }
}

// out = x + ((x * SE_b) * S^T) via split-bf16 MFMA, LDS-staged x (hi/lo).
// 16-row tiles, n-split waves, XPAD=524. Byte-identical to R18-R20. grid (256, 8).
__global__ __launch_bounds__(256, 4) void k_mix(const float* x,
                                                const unsigned short* SEf,
                                                const unsigned short* Sf,
                                                float* out) {
    __shared__ unsigned short xh[16 * XPAD];
    __shared__ unsigned short xl[16 * XPAD];
    __shared__ float Zs[16 * 68];
    const int b = blockIdx.y;
    const int r0 = blockIdx.x * 16;
    const int t = threadIdx.x;
    const int w = t >> 6;
    const int l = t & 63;
    const int lm = l & 15;
    const int lk = (l >> 4) * 8;
    const float* xb = x + (size_t)b * N_ * F_;
    float* outb = out + (size_t)b * N_ * F_;
    const unsigned short* sef = SEf + (size_t)b * 65536;

#pragma unroll 4
    for (int it = 0; it < 8; ++it) {
        const int idx = it * 256 + t;
        const int row = idx >> 7, c4 = (idx & 127) * 4;
        const float4 v = *reinterpret_cast<const float4*>(
            xb + (size_t)(r0 + row) * F_ + c4);
        ushort4 hs, ls;
        short hh, ss;
        bf16_split(v.x, hh, ss); hs.x = (unsigned short)hh; ls.x = (unsigned short)ss;
        bf16_split(v.y, hh, ss); hs.y = (unsigned short)hh; ls.y = (unsigned short)ss;
        bf16_split(v.z, hh, ss); hs.z = (unsigned short)hh; ls.z = (unsigned short)ss;
        bf16_split(v.w, hh, ss); hs.w = (unsigned short)hh; ls.w = (unsigned short)ss;
        *reinterpret_cast<ushort4*>(&xh[row * XPAD + c4]) = hs;
        *reinterpret_cast<ushort4*>(&xl[row * XPAD + c4]) = ls;
    }
    __syncthreads();

    f32x4 ahh = {0.f, 0.f, 0.f, 0.f}, alh = ahh, ahl = ahh;
    const unsigned short* xhr = xh + lm * XPAD;
    const unsigned short* xlr = xl + lm * XPAD;
#pragma unroll 4
    for (int kk = 0; kk < 16; ++kk) {
        const int k0 = kk * 32 + lk;
        const bf16x8 ah = *reinterpret_cast<const bf16x8*>(xhr + k0);
        const bf16x8 al = *reinterpret_cast<const bf16x8*>(xlr + k0);
        const int o0 = (kk * 4 + w) * 1024 + l * 8;
        const bf16x8 bh = *reinterpret_cast<const bf16x8*>(sef + o0);
        const bf16x8 bl = *reinterpret_cast<const bf16x8*>(sef + o0 + 512);
        ahh = __builtin_amdgcn_mfma_f32_16x16x32_bf16(ah, bh, ahh, 0, 0, 0);
        alh = __builtin_amdgcn_mfma_f32_16x16x32_bf16(al, bh, alh, 0, 0, 0);
        ahl = __builtin_amdgcn_mfma_f32_16x16x32_bf16(ah, bl, ahl, 0, 0, 0);
    }
#pragma unroll
    for (int r = 0; r < 4; ++r) {
        const int zr = ((l >> 4) * 4 + r) * 68 + w * 16;
        Zs[zr + lm] = ahh[r] + alh[r] + ahl[r];
    }
    __syncthreads();

    bf16x8 zh0, zl0, zh1, zl1;
    {
        const float* zrow = &Zs[lm * 68];
#pragma unroll
        for (int i = 0; i < 8; ++i) {
            short hh, ss;
            bf16_split(zrow[lk + i], hh, ss);
            zh0[i] = hh; zl0[i] = ss;
            bf16_split(zrow[32 + lk + i], hh, ss);
            zh1[i] = hh; zl1[i] = ss;
        }
    }
    const int lrow0 = (l >> 4) * 4;
    const int orow0 = r0 + lrow0;
#pragma unroll 2
    for (int j2 = 0; j2 < 8; ++j2) {
        const int ht = w * 8 + j2;
        const int h0 = ht * 16 + lm;
        f32x4 ca = {0.f, 0.f, 0.f, 0.f};
        f32x4 cb;
#pragma unroll
        for (int r = 0; r < 4; ++r) {
            const int la = (lrow0 + r) * XPAD + h0;
            cb[r] = b2f(xh[la]) + b2f(xl[la]);
        }
        const int fb = ht * 2048 + l * 8;
        const bf16x8 bh0 = *reinterpret_cast<const bf16x8*>(Sf + fb);
        const bf16x8 bl0 = *reinterpret_cast<const bf16x8*>(Sf + fb + 512);
        const bf16x8 bh1 = *reinterpret_cast<const bf16x8*>(Sf + fb + 1024);
        const bf16x8 bl1 = *reinterpret_cast<const bf16x8*>(Sf + fb + 1536);
        ca = __builtin_amdgcn_mfma_f32_16x16x32_bf16(zh0, bh0, ca, 0, 0, 0);
        ca = __builtin_amdgcn_mfma_f32_16x16x32_bf16(zl0, bh0, ca, 0, 0, 0);
        ca = __builtin_amdgcn_mfma_f32_16x16x32_bf16(zh0, bl0, ca, 0, 0, 0);
        cb = __builtin_amdgcn_mfma_f32_16x16x32_bf16(zh1, bh1, cb, 0, 0, 0);
        cb = __builtin_amdgcn_mfma_f32_16x16x32_bf16(zl1, bh1, cb, 0, 0, 0);
        cb = __builtin_amdgcn_mfma_f32_16x16x32_bf16(zh1, bl1, cb, 0, 0, 0);
#pragma unroll
        for (int r = 0; r < 4; ++r)
            outb[(size_t)(orow0 + r) * F_ + h0] = ca[r] + cb[r];
    }
}

extern "C" void kernel_launch(void* const* d_in, const int* in_sizes, int n_in,
                              void* d_out, int out_size, void* d_ws, size_t ws_size,
                              hipStream_t stream) {
    (void)in_sizes; (void)n_in; (void)out_size; (void)ws_size;
    const float* x       = (const float*)d_in[0];
    const float* coeff   = (const float*)d_in[1];
    const float* gate    = (const float*)d_in[2];
    const float* coeff_l = (const float*)d_in[3];
    const float* gate_l  = (const float*)d_in[4];
    const float* comm    = (const float*)d_in[5];
    const float* l       = (const float*)d_in[6];
    const float* r       = (const float*)d_in[7];
    const float* ll      = (const float*)d_in[8];
    const float* rl      = (const float*)d_in[9];

    char* wsb = (char*)d_ws;
    float* GS   = (float*)(wsb);                              // 4096 f       @0
    unsigned short* SEf = (unsigned short*)(wsb + 147456);    // 8*65536 u16  @144K (1MB)
    unsigned short* Sf  = (unsigned short*)(wsb + 1196032);   // 65536 u16    @1168K (128K)
    float* CPws = (float*)(wsb + 1458176);                    // 8*4096 f     @1424K
    float* Kws  = (float*)(wsb + 1589248);                    // 8*4096 f     @1552K (ends 1680K)
    float* out = (float*)d_out;

    k_prep<<<dim3(64), dim3(256), 0, stream>>>(l, r, ll, rl, GS, Sf);
    k_presolve<<<dim3(8), dim3(256), 0, stream>>>(coeff, gate, coeff_l, gate_l, comm,
                                                  GS, CPws, Kws);
    k_sepost<<<dim3(8, 8), dim3(256), 0, stream>>>(coeff, coeff_l, l, r, ll, rl,
                                                   CPws, Kws, SEf);
    k_mix<<<dim3(256, 8), dim3(256), 0, stream>>>(x, SEf, Sf, out);
}